// Round 5
// baseline (2787.907 us; speedup 1.0000x reference)
//
#include <hip/hip_runtime.h>
#include <hip/hip_cooperative_groups.h>

namespace cg = cooperative_groups;

typedef __attribute__((ext_vector_type(8))) short short8;
typedef __attribute__((ext_vector_type(4))) float f32x4;

__device__ __forceinline__ unsigned short f2bf(float x){
  union { float f; unsigned u; } v; v.f = x;
  unsigned r = v.u + 0x7fffu + ((v.u >> 16) & 1u);
  return (unsigned short)(r >> 16);
}
__device__ __forceinline__ float sigm(float x){ return 1.0f / (1.0f + __expf(-x)); }
__device__ __forceinline__ float tanh_(float x){
  float e = __expf(2.0f * x);
  return 1.0f - 2.0f / (e + 1.0f);
}
__device__ __forceinline__ short8 load_bf8_f32(const float* p){
  float4 a = *(const float4*)p;
  float4 b = *(const float4*)(p + 4);
  short8 r;
  r[0]=(short)f2bf(a.x); r[1]=(short)f2bf(a.y); r[2]=(short)f2bf(a.z); r[3]=(short)f2bf(a.w);
  r[4]=(short)f2bf(b.x); r[5]=(short)f2bf(b.y); r[6]=(short)f2bf(b.z); r[7]=(short)f2bf(b.w);
  return r;
}
__device__ __forceinline__ f32x4 mfma16(short8 a, short8 b, f32x4 c){
  return __builtin_amdgcn_mfma_f32_16x16x32_bf16(a, b, c, 0, 0, 0);
}
__device__ __forceinline__ void gload16(const void* g, void* lds){
  __builtin_amdgcn_global_load_lds((const __attribute__((address_space(1))) void*)g,
                                   (__attribute__((address_space(3))) void*)lds, 16, 0, 0);
}
__device__ __forceinline__ f32x4 shfl_xor4(f32x4 v, int m){
  f32x4 r;
  r[0]=__shfl_xor(v[0],m); r[1]=__shfl_xor(v[1],m);
  r[2]=__shfl_xor(v[2],m); r[3]=__shfl_xor(v[3],m);
  return r;
}
__device__ __forceinline__ float pick4(f32x4 v, int k){
  float a = (k&1)? v[1] : v[0];
  float b = (k&1)? v[3] : v[2];
  return (k&2)? b : a;
}
__device__ __forceinline__ f32x4 sel4(f32x4 a0, f32x4 a1, f32x4 a2, f32x4 a3, int k){
  f32x4 x = (k&1)? a1 : a0;
  f32x4 y = (k&1)? a3 : a2;
  return (k&2)? y : x;
}

// ================= 128x128 MFMA GEMM K-loop (m97 structure) =================
#define KLOOP_BODY(ABASE, BBASE)                                                     \
  for (int kt = 0; kt < 8; ++kt){                                                    \
    _Pragma("unroll")                                                                \
    for (int q = 0; q < 4; ++q){                                                     \
      gload16(ABASE[q] + kt*64, &As[(q*32 + w*8)*64]);                               \
      gload16(BBASE[q] + kt*64, &Bs[(q*32 + w*8)*64]);                               \
    }                                                                                \
    __syncthreads();                                                                 \
    _Pragma("unroll")                                                                \
    for (int kk = 0; kk < 2; ++kk){                                                  \
      short8 av[4], bv[4];                                                           \
      _Pragma("unroll")                                                              \
      for (int i = 0; i < 4; ++i) av[i] = *(const short8*)&As[(wm*64 + i*16 + r15)*64 + kk*32 + g4*8]; \
      _Pragma("unroll")                                                              \
      for (int i = 0; i < 4; ++i) bv[i] = *(const short8*)&Bs[(wn*64 + i*16 + r15)*64 + kk*32 + g4*8]; \
      _Pragma("unroll")                                                              \
      for (int i = 0; i < 4; ++i)                                                    \
        _Pragma("unroll")                                                            \
        for (int j = 0; j < 4; ++j) acc[i][j] = mfma16(av[i], bv[j], acc[i][j]);     \
    }                                                                                \
    __syncthreads();                                                                 \
  }

// ---------------- prep: converts, remaps, transpose, bias folds, sorts ----------------
__global__ __launch_bounds__(256) void prep_kernel(
    const float* __restrict__ emb, const int* __restrict__ dep,
    const float* __restrict__ W_dep, const float* __restrict__ b_dep,
    const float* __restrict__ W_ih, const float* __restrict__ W_hh,
    const float* __restrict__ b_ih, const float* __restrict__ b_hh,
    unsigned short* __restrict__ embb, unsigned short* __restrict__ Wih_il,
    unsigned short* __restrict__ Whh_il, unsigned short* __restrict__ Wleaf,
    unsigned short* __restrict__ WdT, float* __restrict__ bsum, float* __restrict__ bc,
    int* __restrict__ perm, int* __restrict__ tile_p, int* __restrict__ meta)
{
  const int bid = blockIdx.x, tid = threadIdx.x;
  if (bid < 1024){
    for (size_t i = (size_t)bid*256 + tid; i < 2396736ull; i += 1024ull*256)
      *(short8*)(embb + i*8) = load_bf8_f32(emb + i*8);
  } else if (bid < 1536){
    int idx = (bid-1024)*256 + tid; int r = idx >> 6, c8 = idx & 63;
    int sr = (r & 3)*512 + (r >> 2);
    *(short8*)(Wih_il + (size_t)r*512 + c8*8) = load_bf8_f32(W_ih + (size_t)sr*512 + c8*8);
  } else if (bid < 2048){
    int idx = (bid-1536)*256 + tid; int r = idx >> 6, c8 = idx & 63;
    int sr = (r & 3)*512 + (r >> 2);
    *(short8*)(Whh_il + (size_t)r*512 + c8*8) = load_bf8_f32(W_hh + (size_t)sr*512 + c8*8);
  } else if (bid < 2304){
    int idx = (bid-2048)*256 + tid; int r = idx >> 6, c8 = idx & 63;
    int sr = ((r & 1) ? 2 : 0)*512 + (r >> 1);
    *(short8*)(Wleaf + (size_t)r*512 + c8*8) = load_bf8_f32(W_ih + (size_t)sr*512 + c8*8);
  } else if (bid < 2816){
    __shared__ unsigned short tle[64][65];
    int lb = bid - 2304; int p = lb >> 6; int tile = lb & 63;
    int i0 = (tile >> 3)*64, j0 = (tile & 7)*64;
    const float* src = W_dep + (size_t)p*512*512;
    for (int q = 0; q < 16; ++q){
      int e = q*256 + tid; int li = e >> 6, lj = e & 63;
      tle[li][lj] = f2bf(src[(size_t)(i0+li)*512 + (j0+lj)]);
    }
    __syncthreads();
    unsigned short* dst = WdT + (size_t)p*512*512;
    for (int q = 0; q < 16; ++q){
      int e = q*256 + tid; int lj = e >> 6, li = e & 63;
      dst[(size_t)(j0+lj)*512 + (i0+li)] = tle[li][lj];
    }
  } else if (bid < 2824){
    int r = (bid-2816)*256 + tid;
    if (r < 2048){ int g = r & 3, j = r >> 2; bsum[r] = b_ih[g*512+j] + b_hh[g*512+j]; }
  } else if (bid < 2888){
    __shared__ float bd[512];
    int lb = bid - 2824; int p = lb >> 3, ch = lb & 7;
    for (int i = tid; i < 512; i += 256) bd[i] = b_dep[p*512 + i];
    __syncthreads();
    int r = ch*256 + tid; int g = r & 3, j = r >> 2;
    const float* wr = W_ih + (size_t)(g*512 + j)*512;
    float s = 0.0f;
    for (int i = 0; i < 512; ++i) s = fmaf(wr[i], bd[i], s);
    bc[(size_t)p*2048 + r] = s;
  } else {
    __shared__ int cnt[8], base[8], fill[8];
    int lb = bid - 2888; const int l = lb >> 3, t = lb & 7;
    const int M_[5]  = {1,8,64,512,4096};
    const int CB_[5] = {1,9,73,585,4681};
    const int MT_[5] = {8,8,8,12,40};
    const int PB_[5] = {69632,61440,53248,40960,0};
    const int TB_[5] = {544,480,416,320,0};
    const int m = M_[l], cb = CB_[l], MT = MT_[l];
    int* pm = perm + PB_[l] + t*MT*128;
    int* tp = tile_p + TB_[l] + t*MT;
    if (tid < 8){ cnt[tid] = 0; fill[tid] = 0; }
    __syncthreads();
    for (int n = tid; n < m; n += 256) atomicAdd(&cnt[dep[cb + n*8 + t]], 1);
    __syncthreads();
    if (tid == 0){
      int tiles = 0;
      for (int p = 0; p < 8; ++p){
        base[p] = tiles*128;
        int g = (cnt[p] + 127) >> 7;
        for (int q = 0; q < g; ++q) tp[tiles + q] = p;
        tiles += g;
      }
      meta[l*8 + t] = tiles;
    }
    __syncthreads();
    for (int i = tid; i < MT*128; i += 256) pm[i] = -1;
    __syncthreads();
    for (int n = tid; n < m; n += 256){
      int p = dep[cb + n*8 + t];
      pm[base[p] + atomicAdd(&fill[p], 1)] = n;
    }
  }
}

// ---------------- persistent tree kernel (phases; coop-syncs between) ----------------
struct TreeArgs {
  const unsigned short* embb;
  const unsigned short* Wih_il;
  const unsigned short* Whh_il;
  const unsigned short* Wleaf;
  const unsigned short* WdT;
  unsigned short* Wcombo;
  unsigned short* Z0;
  unsigned short* Z1;
  unsigned short* hA;
  unsigned short* hB;
  float* cbuf;
  const float* bsum;
  const float* bc;
  const int* perm;
  const int* tile_p;
  const int* meta;
  float* out;
};

// phase 0: Wcombo GEMM (512 jobs) + leaf GEMM (2048 jobs)
// phase 1..45: s = phase-1; l = 4 - s/9; t = s%9  (t<8: child step, t==8: emb step)
__global__ __launch_bounds__(256, 2) void tree_kernel(TreeArgs a, int phase_lo, int phase_hi)
{
  cg::grid_group gg = cg::this_grid();
  __shared__ unsigned short As[128*64];
  __shared__ unsigned short Bs[128*64];
  const int tid = threadIdx.x, lane = tid & 63, w = tid >> 6;
  const int wm = w >> 1, wn = w & 1;
  const int r15 = lane & 15, g4 = lane >> 4;
  const int kc = (lane & 7)*8;
  const int GS = gridDim.x;

  for (int ph = phase_lo; ph <= phase_hi; ++ph){
    if (ph == 0){
      for (int job = blockIdx.x; job < 2560; job += GS){
        if (job < 512){
          const int p = job >> 6, mt = (job >> 2) & 15, nbq = job & 3;
          const unsigned short* ab[4]; const unsigned short* bb[4];
          #pragma unroll
          for (int q = 0; q < 4; ++q){
            int rl = mt*128 + q*32 + w*8 + (lane >> 3);
            ab[q] = a.Wih_il + (size_t)rl*512 + kc;
            int br = nbq*128 + q*32 + w*8 + (lane >> 3);
            bb[q] = a.WdT + (size_t)p*262144 + (size_t)br*512 + kc;
          }
          f32x4 acc[4][4] = {};
          KLOOP_BODY(ab, bb)
          unsigned short* Cp = a.Wcombo + (size_t)p*1048576;
          #pragma unroll
          for (int mi = 0; mi < 4; ++mi)
            #pragma unroll
            for (int ni = 0; ni < 4; ++ni)
              #pragma unroll
              for (int j = 0; j < 4; ++j){
                int row = mt*128 + wm*64 + mi*16 + g4*4 + j;
                int col = nbq*128 + wn*64 + ni*16 + r15;
                Cp[(size_t)row*512 + col] = f2bf(acc[mi][ni][j]);
              }
        } else {
          const int lj = job - 512;
          const int mt = lj >> 3, nbq = lj & 7;
          const unsigned short* ab[4]; const unsigned short* bb[4];
          #pragma unroll
          for (int q = 0; q < 4; ++q){
            int rl = mt*128 + q*32 + w*8 + (lane >> 3);
            ab[q] = a.embb + (size_t)(4681 + rl)*512 + kc;
            int br = nbq*128 + q*32 + w*8 + (lane >> 3);
            bb[q] = a.Wleaf + (size_t)br*512 + kc;
          }
          f32x4 acc[4][4] = {};
          KLOOP_BODY(ab, bb)
          const int g2 = r15 & 1;
          #pragma unroll
          for (int ni = 0; ni < 4; ++ni){
            int ci = nbq*128 + wn*64 + ni*16 + r15;
            float b = a.bsum[4*(ci >> 1) + (g2 ? 2 : 0)];
            #pragma unroll
            for (int mi = 0; mi < 4; ++mi){
              acc[mi][ni][0]+=b; acc[mi][ni][1]+=b; acc[mi][ni][2]+=b; acc[mi][ni][3]+=b;
            }
          }
          #pragma unroll
          for (int mi = 0; mi < 4; ++mi)
            #pragma unroll
            for (int ni = 0; ni < 4; ++ni){
              f32x4 a0 = acc[mi][ni];
              f32x4 a1 = shfl_xor4(a0, 1);
              f32x4 vi_ = g2 ? a1 : a0;
              f32x4 vg_ = g2 ? a0 : a1;
              int jz = (nbq*128 + wn*64 + ni*16 + r15) >> 1;
              #pragma unroll
              for (int u = 0; u < 2; ++u){
                int jrow = (g2 << 1) + u;
                float zi = pick4(vi_, jrow), zg = pick4(vg_, jrow);
                int row = mt*128 + wm*64 + mi*16 + g4*4 + jrow;
                a.Z0[(size_t)row*512 + jz] = f2bf(sigm(zi) * tanh_(zg));
              }
            }
        }
      }
    } else {
      const int s = ph - 1;
      const int dl = s / 9;
      const int l = 4 - dl;
      const int t = s - dl*9;
      const int m = 1 << (3*l);
      const int node_base = (m - 1) / 7;
      int MT, PB, TB;
      if (l == 4)      { MT = 40; PB = 0;     TB = 0;   }
      else if (l == 3) { MT = 12; PB = 40960; TB = 320; }
      else if (l == 2) { MT = 8;  PB = 53248; TB = 416; }
      else if (l == 1) { MT = 8;  PB = 61440; TB = 480; }
      else             { MT = 8;  PB = 69632; TB = 544; }
      const unsigned short* zin = (l & 1) ? a.Z1 : a.Z0;
      unsigned short* zo        = (l & 1) ? a.Z0 : a.Z1;
      const int first = (t == 0), last = (t == 8);
      const unsigned short* hi = (t & 1) ? a.hA : a.hB;
      unsigned short* ho       = (t & 1) ? a.hB : a.hA;

      int njobs; const int* pm = nullptr; const int* tp = nullptr;
      if (t < 8){
        int ntiles = a.meta[l*8 + t]; if (ntiles > MT) ntiles = MT;
        njobs = ntiles * 16;
        pm = a.perm + PB + t*MT*128;
        tp = a.tile_p + TB + t*MT;
      } else {
        njobs = ((m + 127) >> 7) * 16;
      }

      for (int job = blockIdx.x; job < njobs; job += GS){
        const int mt = job >> 4, nbq = job & 15;
        const int p = (t < 8) ? tp[mt] : 0;
        int nn[4];
        #pragma unroll
        for (int q = 0; q < 4; ++q){
          int rl = mt*128 + q*32 + w*8 + (lane >> 3);
          int n = (t < 8) ? pm[rl] : (rl < m ? rl : -1);
          nn[q] = (n < 0) ? 0 : n;
        }
        f32x4 acc[4][4] = {};
        { // X phase
          const unsigned short* Bx = (t < 8) ? (a.Wcombo + (size_t)p*1048576) : a.Wih_il;
          const unsigned short* ab[4]; const unsigned short* bb[4];
          #pragma unroll
          for (int q = 0; q < 4; ++q){
            ab[q] = (t < 8) ? (zin + ((size_t)nn[q]*8 + t)*512 + kc)
                            : (a.embb + (size_t)(node_base + nn[q])*512 + kc);
            int br = nbq*128 + q*32 + w*8 + (lane >> 3);
            bb[q] = Bx + (size_t)br*512 + kc;
          }
          KLOOP_BODY(ab, bb)
        }
        if (!first){ // H phase
          const unsigned short* ab[4]; const unsigned short* bb[4];
          #pragma unroll
          for (int q = 0; q < 4; ++q){
            ab[q] = hi + (size_t)nn[q]*512 + kc;
            int br = nbq*128 + q*32 + w*8 + (lane >> 3);
            bb[q] = a.Whh_il + (size_t)br*512 + kc;
          }
          KLOOP_BODY(ab, bb)
        }
        const int gate = r15 & 3;
        #pragma unroll
        for (int ni = 0; ni < 4; ++ni){
          int ci = nbq*128 + wn*64 + ni*16 + r15;
          float b = a.bsum[ci] + ((t < 8) ? a.bc[(size_t)p*2048 + ci] : 0.0f);
          #pragma unroll
          for (int mi = 0; mi < 4; ++mi){
            acc[mi][ni][0]+=b; acc[mi][ni][1]+=b; acc[mi][ni][2]+=b; acc[mi][ni][3]+=b;
          }
        }
        const int jr = r15 & 3;
        #pragma unroll
        for (int mi = 0; mi < 4; ++mi){
          int rl = mt*128 + wm*64 + mi*16 + g4*4 + jr;
          int n = (t < 8) ? pm[rl] : (rl < m ? rl : -1);
          #pragma unroll
          for (int ni = 0; ni < 4; ++ni){
            f32x4 a0 = acc[mi][ni];
            f32x4 a1 = shfl_xor4(a0, 1);
            f32x4 a2 = shfl_xor4(a0, 2);
            f32x4 a3 = shfl_xor4(a1, 2);
            f32x4 vi_ = sel4(a0,a1,a2,a3, gate);
            f32x4 vf_ = sel4(a0,a1,a2,a3, gate^1);
            f32x4 vg_ = sel4(a0,a1,a2,a3, gate^2);
            f32x4 vo_ = sel4(a0,a1,a2,a3, gate^3);
            float xi = pick4(vi_, jr), xf = pick4(vf_, jr);
            float xg = pick4(vg_, jr), xo = pick4(vo_, jr);
            if (n >= 0){
              int jz = nbq*32 + wn*16 + ni*4 + (r15 >> 2);
              size_t idx = (size_t)n*512 + jz;
              float i_ = sigm(xi), f_ = sigm(xf), g_ = tanh_(xg), o_ = sigm(xo);
              float cold = first ? 0.0f : a.cbuf[idx];
              float cn = fmaf(f_, cold, i_*g_);
              if (!last){ a.cbuf[idx] = cn; ho[idx] = f2bf(o_*tanh_(cn)); }
              else { if (l > 0) zo[idx] = f2bf(cn); else a.out[idx] = cn; }
            }
          }
        }
      }
    }
    if (ph != phase_hi) gg.sync();
  }
}

// OFF = {0, 1, 9, 73, 585, 4681, 37449}
extern "C" void kernel_launch(void* const* d_in, const int* in_sizes, int n_in,
                              void* d_out, int out_size, void* d_ws, size_t ws_size,
                              hipStream_t stream)
{
  (void)in_sizes; (void)n_in; (void)out_size; (void)ws_size;
  const float* emb   = (const float*)d_in[0];
  const int*   dep   = (const int*)  d_in[1];
  const float* W_dep = (const float*)d_in[2];
  const float* b_dep = (const float*)d_in[3];
  const float* W_ih  = (const float*)d_in[4];
  const float* W_hh  = (const float*)d_in[5];
  const float* b_ih  = (const float*)d_in[6];
  const float* b_hh  = (const float*)d_in[7];
  float* out = (float*)d_out;

  unsigned short* embb   = (unsigned short*)d_ws;                  // 37449*512
  unsigned short* Wih_il = embb   + 19173888ull;                   // 2048*512
  unsigned short* Whh_il = Wih_il + 1048576ull;                    // 2048*512
  unsigned short* Wleaf  = Whh_il + 1048576ull;                    // 1024*512
  unsigned short* WdT    = Wleaf  + 524288ull;                     // 8*512*512
  unsigned short* Wcombo = WdT    + 2097152ull;                    // 8*2048*512
  unsigned short* Z0     = Wcombo + 8388608ull;                    // 32768*512
  unsigned short* Z1     = Z0     + 16777216ull;                   // 4096*512
  unsigned short* hA     = Z1     + 2097152ull;                    // 4096*512
  unsigned short* hB     = hA     + 2097152ull;                    // 4096*512
  float* cbuf  = (float*)(hB + 2097152ull);                        // 4096*512 f32
  float* bsum  = cbuf + 2097152ull;                                // 2048
  float* bc    = bsum + 2048;                                      // 8*2048
  int*  perm   = (int*)(bc + 16384);                               // 77824
  int*  tile_p = perm + 77824;                                     // 608
  int*  meta   = tile_p + 608;                                     // 40

  prep_kernel<<<2928, 256, 0, stream>>>(emb, dep, W_dep, b_dep, W_ih, W_hh, b_ih, b_hh,
                                        embb, Wih_il, Whh_il, Wleaf, WdT, bsum, bc,
                                        perm, tile_p, meta);

  TreeArgs ta;
  ta.embb = embb; ta.Wih_il = Wih_il; ta.Whh_il = Whh_il; ta.Wleaf = Wleaf;
  ta.WdT = WdT; ta.Wcombo = Wcombo; ta.Z0 = Z0; ta.Z1 = Z1; ta.hA = hA; ta.hB = hB;
  ta.cbuf = cbuf; ta.bsum = bsum; ta.bc = bc; ta.perm = perm; ta.tile_p = tile_p;
  ta.meta = meta; ta.out = out;

  // size the cooperative grid by the runtime's own admission criterion
  int cap = 0, nCU = 0, dev = 0;
  (void)hipGetDevice(&dev);
  (void)hipOccupancyMaxActiveBlocksPerMultiprocessor(&cap, tree_kernel, 256, 0);
  (void)hipDeviceGetAttribute(&nCU, hipDeviceAttributeMultiprocessorCount, dev);
  if (nCU <= 0) nCU = 256;
  long capacity = (long)cap * nCU;
  int gsz = (int)((capacity < 640) ? capacity : 640);

  hipError_t ce = hipErrorUnknown;
  if (gsz >= 64){
    int plo = 0, phi = 45;
    void* kp[3] = { &ta, &plo, &phi };
    ce = hipLaunchCooperativeKernel((const void*)tree_kernel, dim3(gsz), dim3(256),
                                    kp, 0, stream);
  }
  if (ce != hipSuccess){
    // fallback: one ordinary launch per phase (no grid sync executed inside)
    for (int ph = 0; ph <= 45; ++ph){
      int grid;
      if (ph == 0) grid = 2560;
      else {
        int s = ph - 1, dl = s/9, l = 4 - dl, t = s - dl*9;
        int m = 1 << (3*l);
        int MT = (l == 4) ? 40 : (l == 3) ? 12 : 8;
        grid = (t < 8) ? MT*16 : ((m + 127) >> 7)*16;
      }
      tree_kernel<<<grid, 256, 0, stream>>>(ta, ph, ph);
    }
  }
}

// Round 6
// 2193.429 us; speedup vs baseline: 1.2710x; 1.2710x over previous
//
#include <hip/hip_runtime.h>

typedef __attribute__((ext_vector_type(8))) short short8;
typedef __attribute__((ext_vector_type(4))) float f32x4;

__device__ __forceinline__ unsigned short f2bf(float x){
  union { float f; unsigned u; } v; v.f = x;
  unsigned r = v.u + 0x7fffu + ((v.u >> 16) & 1u);
  return (unsigned short)(r >> 16);
}
__device__ __forceinline__ float sigm(float x){ return 1.0f / (1.0f + __expf(-x)); }
__device__ __forceinline__ float tanh_(float x){
  float e = __expf(2.0f * x);
  return 1.0f - 2.0f / (e + 1.0f);
}
__device__ __forceinline__ short8 load_bf8_f32(const float* p){
  float4 a = *(const float4*)p;
  float4 b = *(const float4*)(p + 4);
  short8 r;
  r[0]=(short)f2bf(a.x); r[1]=(short)f2bf(a.y); r[2]=(short)f2bf(a.z); r[3]=(short)f2bf(a.w);
  r[4]=(short)f2bf(b.x); r[5]=(short)f2bf(b.y); r[6]=(short)f2bf(b.z); r[7]=(short)f2bf(b.w);
  return r;
}
__device__ __forceinline__ f32x4 mfma16(short8 a, short8 b, f32x4 c){
  return __builtin_amdgcn_mfma_f32_16x16x32_bf16(a, b, c, 0, 0, 0);
}
__device__ __forceinline__ void gload16(const void* g, void* lds){
  __builtin_amdgcn_global_load_lds((const __attribute__((address_space(1))) void*)g,
                                   (__attribute__((address_space(3))) void*)lds, 16, 0, 0);
}
__device__ __forceinline__ f32x4 shfl_xor4(f32x4 v, int m){
  f32x4 r;
  r[0]=__shfl_xor(v[0],m); r[1]=__shfl_xor(v[1],m);
  r[2]=__shfl_xor(v[2],m); r[3]=__shfl_xor(v[3],m);
  return r;
}
__device__ __forceinline__ float pick4(f32x4 v, int k){
  float a = (k&1)? v[1] : v[0];
  float b = (k&1)? v[3] : v[2];
  return (k&2)? b : a;
}
__device__ __forceinline__ f32x4 sel4(f32x4 a0, f32x4 a1, f32x4 a2, f32x4 a3, int k){
  f32x4 x = (k&1)? a1 : a0;
  f32x4 y = (k&1)? a3 : a2;
  return (k&2)? y : x;
}

// lightweight co-resident-grid barrier (monotone counter, zeroed by prep)
__device__ __forceinline__ void gridbar(int* ctr, int target){
  __syncthreads();
  if (threadIdx.x == 0){
    __threadfence();
    __hip_atomic_fetch_add(ctr, 1, __ATOMIC_ACQ_REL, __HIP_MEMORY_SCOPE_AGENT);
    while (__hip_atomic_load(ctr, __ATOMIC_ACQUIRE, __HIP_MEMORY_SCOPE_AGENT) < target){
      __builtin_amdgcn_s_sleep(8);
    }
  }
  __syncthreads();
}

// ================= 128x128 MFMA GEMM K-loop (m97 structure) =================
#define KLOOP_BODY(ABASE, BBASE)                                                     \
  for (int kt = 0; kt < 8; ++kt){                                                    \
    _Pragma("unroll")                                                                \
    for (int q = 0; q < 4; ++q){                                                     \
      gload16(ABASE[q] + kt*64, &As[(q*32 + w*8)*64]);                               \
      gload16(BBASE[q] + kt*64, &Bs[(q*32 + w*8)*64]);                               \
    }                                                                                \
    __syncthreads();                                                                 \
    _Pragma("unroll")                                                                \
    for (int kk = 0; kk < 2; ++kk){                                                  \
      short8 av[4], bv[4];                                                           \
      _Pragma("unroll")                                                              \
      for (int i = 0; i < 4; ++i) av[i] = *(const short8*)&As[(wm*64 + i*16 + r15)*64 + kk*32 + g4*8]; \
      _Pragma("unroll")                                                              \
      for (int i = 0; i < 4; ++i) bv[i] = *(const short8*)&Bs[(wn*64 + i*16 + r15)*64 + kk*32 + g4*8]; \
      _Pragma("unroll")                                                              \
      for (int i = 0; i < 4; ++i)                                                    \
        _Pragma("unroll")                                                            \
        for (int j = 0; j < 4; ++j) acc[i][j] = mfma16(av[i], bv[j], acc[i][j]);     \
    }                                                                                \
    __syncthreads();                                                                 \
  }

// ---------------- prep: converts, remaps, transpose, bias folds, sorts ----------------
__global__ __launch_bounds__(256) void prep_kernel(
    const float* __restrict__ emb, const int* __restrict__ dep,
    const float* __restrict__ W_dep, const float* __restrict__ b_dep,
    const float* __restrict__ W_ih, const float* __restrict__ W_hh,
    const float* __restrict__ b_ih, const float* __restrict__ b_hh,
    unsigned short* __restrict__ embb, unsigned short* __restrict__ Wih_il,
    unsigned short* __restrict__ Whh_il, unsigned short* __restrict__ Wleaf,
    unsigned short* __restrict__ WdT, float* __restrict__ bsum, float* __restrict__ bc,
    int* __restrict__ perm, int* __restrict__ tile_p, int* __restrict__ meta,
    int* __restrict__ ctr)
{
  const int bid = blockIdx.x, tid = threadIdx.x;
  if (bid < 1024){
    for (size_t i = (size_t)bid*256 + tid; i < 2396736ull; i += 1024ull*256)
      *(short8*)(embb + i*8) = load_bf8_f32(emb + i*8);
  } else if (bid < 1536){
    int idx = (bid-1024)*256 + tid; int r = idx >> 6, c8 = idx & 63;
    int sr = (r & 3)*512 + (r >> 2);
    *(short8*)(Wih_il + (size_t)r*512 + c8*8) = load_bf8_f32(W_ih + (size_t)sr*512 + c8*8);
  } else if (bid < 2048){
    int idx = (bid-1536)*256 + tid; int r = idx >> 6, c8 = idx & 63;
    int sr = (r & 3)*512 + (r >> 2);
    *(short8*)(Whh_il + (size_t)r*512 + c8*8) = load_bf8_f32(W_hh + (size_t)sr*512 + c8*8);
  } else if (bid < 2304){
    int idx = (bid-2048)*256 + tid; int r = idx >> 6, c8 = idx & 63;
    int sr = ((r & 1) ? 2 : 0)*512 + (r >> 1);
    *(short8*)(Wleaf + (size_t)r*512 + c8*8) = load_bf8_f32(W_ih + (size_t)sr*512 + c8*8);
  } else if (bid < 2816){
    __shared__ unsigned short tle[64][65];
    int lb = bid - 2304; int p = lb >> 6; int tile = lb & 63;
    int i0 = (tile >> 3)*64, j0 = (tile & 7)*64;
    const float* src = W_dep + (size_t)p*512*512;
    for (int q = 0; q < 16; ++q){
      int e = q*256 + tid; int li = e >> 6, lj = e & 63;
      tle[li][lj] = f2bf(src[(size_t)(i0+li)*512 + (j0+lj)]);
    }
    __syncthreads();
    unsigned short* dst = WdT + (size_t)p*512*512;
    for (int q = 0; q < 16; ++q){
      int e = q*256 + tid; int lj = e >> 6, li = e & 63;
      dst[(size_t)(j0+lj)*512 + (i0+li)] = tle[li][lj];
    }
  } else if (bid < 2824){
    int r = (bid-2816)*256 + tid;
    if (r < 2048){ int g = r & 3, j = r >> 2; bsum[r] = b_ih[g*512+j] + b_hh[g*512+j]; }
  } else if (bid < 2888){
    __shared__ float bd[512];
    int lb = bid - 2824; int p = lb >> 3, ch = lb & 7;
    for (int i = tid; i < 512; i += 256) bd[i] = b_dep[p*512 + i];
    __syncthreads();
    int r = ch*256 + tid; int g = r & 3, j = r >> 2;
    const float* wr = W_ih + (size_t)(g*512 + j)*512;
    float s = 0.0f;
    for (int i = 0; i < 512; ++i) s = fmaf(wr[i], bd[i], s);
    bc[(size_t)p*2048 + r] = s;
  } else if (bid < 2928){
    __shared__ int cnt[8], base[8], fill[8];
    int lb = bid - 2888; const int l = lb >> 3, t = lb & 7;
    const int M_[5]  = {1,8,64,512,4096};
    const int CB_[5] = {1,9,73,585,4681};
    const int MT_[5] = {8,8,8,12,40};
    const int PB_[5] = {69632,61440,53248,40960,0};
    const int TB_[5] = {544,480,416,320,0};
    const int m = M_[l], cb = CB_[l], MT = MT_[l];
    int* pm = perm + PB_[l] + t*MT*128;
    int* tp = tile_p + TB_[l] + t*MT;
    if (tid < 8){ cnt[tid] = 0; fill[tid] = 0; }
    __syncthreads();
    for (int n = tid; n < m; n += 256) atomicAdd(&cnt[dep[cb + n*8 + t]], 1);
    __syncthreads();
    if (tid == 0){
      int tiles = 0;
      for (int p = 0; p < 8; ++p){
        base[p] = tiles*128;
        int g = (cnt[p] + 127) >> 7;
        for (int q = 0; q < g; ++q) tp[tiles + q] = p;
        tiles += g;
      }
      meta[l*8 + t] = tiles;
    }
    __syncthreads();
    for (int i = tid; i < MT*128; i += 256) pm[i] = -1;
    __syncthreads();
    for (int n = tid; n < m; n += 256){
      int p = dep[cb + n*8 + t];
      pm[base[p] + atomicAdd(&fill[p], 1)] = n;
    }
  } else {
    if (tid == 0) ctr[0] = 0;
  }
}

// ---- one-time: Wcombo_il[p] = Wih_il @ W_dep[p]^T ----
__global__ __launch_bounds__(256) void combo_gemm(
    const unsigned short* __restrict__ A,
    const unsigned short* __restrict__ WdT,
    unsigned short* __restrict__ C)
{
  const int p  = blockIdx.x >> 6;
  const int mt = (blockIdx.x >> 2) & 15;
  const int nb = blockIdx.x & 3;
  __shared__ unsigned short As[128*64];
  __shared__ unsigned short Bs[128*64];
  const int tid = threadIdx.x, lane = tid & 63, w = tid >> 6;
  const int wm = w >> 1, wn = w & 1;
  const int r15 = lane & 15, g4 = lane >> 4;
  const int kc = (lane & 7)*8;

  const unsigned short* ab[4]; const unsigned short* bb[4];
  #pragma unroll
  for (int q = 0; q < 4; ++q){
    int rl = mt*128 + q*32 + w*8 + (lane >> 3);
    ab[q] = A + (size_t)rl*512 + kc;
    int br = nb*128 + q*32 + w*8 + (lane >> 3);
    bb[q] = WdT + (size_t)p*262144 + (size_t)br*512 + kc;
  }
  f32x4 acc[4][4] = {};
  KLOOP_BODY(ab, bb)
  unsigned short* Cp = C + (size_t)p*1048576;
  #pragma unroll
  for (int mi = 0; mi < 4; ++mi)
    #pragma unroll
    for (int ni = 0; ni < 4; ++ni)
      #pragma unroll
      for (int j = 0; j < 4; ++j){
        int row = mt*128 + wm*64 + mi*16 + g4*4 + j;
        int col = nb*128 + wn*64 + ni*16 + r15;
        Cp[(size_t)row*512 + col] = f2bf(acc[mi][ni][j]);
      }
}

// ---- leaf: z = sigm * tanh (2-gate interleaved B); col-major + XCD chunking ----
__global__ __launch_bounds__(256) void leaf_gemm(
    const unsigned short* __restrict__ embL,
    const unsigned short* __restrict__ Wleaf,
    const float* __restrict__ bsum,
    unsigned short* __restrict__ zo)
{
  const int nb = blockIdx.x & 7;     // col-block pinned per XCD
  const int mt = blockIdx.x >> 3;
  __shared__ unsigned short As[128*64];
  __shared__ unsigned short Bs[128*64];
  const int tid = threadIdx.x, lane = tid & 63, w = tid >> 6;
  const int wm = w >> 1, wn = w & 1;
  const int r15 = lane & 15, g4 = lane >> 4;
  const int kc = (lane & 7)*8;

  const unsigned short* ab[4]; const unsigned short* bb[4];
  #pragma unroll
  for (int q = 0; q < 4; ++q){
    int rl = mt*128 + q*32 + w*8 + (lane >> 3);
    ab[q] = embL + (size_t)rl*512 + kc;
    int br = nb*128 + q*32 + w*8 + (lane >> 3);
    bb[q] = Wleaf + (size_t)br*512 + kc;
  }
  f32x4 acc[4][4] = {};
  KLOOP_BODY(ab, bb)
  const int g2 = r15 & 1;
  #pragma unroll
  for (int ni = 0; ni < 4; ++ni){
    int ci = nb*128 + wn*64 + ni*16 + r15;
    float b = bsum[4*(ci >> 1) + (g2 ? 2 : 0)];
    #pragma unroll
    for (int mi = 0; mi < 4; ++mi){
      acc[mi][ni][0]+=b; acc[mi][ni][1]+=b; acc[mi][ni][2]+=b; acc[mi][ni][3]+=b;
    }
  }
  #pragma unroll
  for (int mi = 0; mi < 4; ++mi)
    #pragma unroll
    for (int ni = 0; ni < 4; ++ni){
      f32x4 a0 = acc[mi][ni];
      f32x4 a1 = shfl_xor4(a0, 1);
      f32x4 vi_ = g2 ? a1 : a0;
      f32x4 vg_ = g2 ? a0 : a1;
      int jz = (nb*128 + wn*64 + ni*16 + r15) >> 1;
      #pragma unroll
      for (int u = 0; u < 2; ++u){
        int jrow = (g2 << 1) + u;
        float zi = pick4(vi_, jrow), zg = pick4(vg_, jrow);
        int row = mt*128 + wm*64 + mi*16 + g4*4 + jrow;
        zo[(size_t)row*512 + jz] = f2bf(sigm(zi) * tanh_(zg));
      }
    }
}

// ---------------- fused recurrent step tile (shared by launches + subtree) ----------------
__device__ __forceinline__ void step_core(
    unsigned short* As, unsigned short* Bs,
    const unsigned short* __restrict__ embb,
    const unsigned short* __restrict__ Wcombo,
    const unsigned short* __restrict__ Wih_il,
    const unsigned short* __restrict__ Whh_il,
    const float* __restrict__ bsum, const float* __restrict__ bc,
    const unsigned short* __restrict__ zin, unsigned short* __restrict__ zo,
    const unsigned short* __restrict__ hi, unsigned short* __restrict__ ho,
    float* __restrict__ cbuf, float* __restrict__ outp,
    const int* __restrict__ pm, const int* __restrict__ tp,
    int node_base, int m, int t, int mt, int nbq, int l)
{
  const int tid = threadIdx.x, lane = tid & 63, w = tid >> 6;
  const int wm = w >> 1, wn = w & 1;
  const int r15 = lane & 15, g4 = lane >> 4;
  const int kc = (lane & 7)*8;
  const int first = (t == 0), last = (t == 8);
  const int p = tp ? tp[mt] : 0;

  int nn[4];
  #pragma unroll
  for (int q = 0; q < 4; ++q){
    int rl = mt*128 + q*32 + w*8 + (lane >> 3);
    int n = pm ? pm[rl] : (rl < m ? rl : -1);
    nn[q] = (n < 0) ? 0 : n;
  }
  f32x4 acc[4][4] = {};
  { // X phase
    const unsigned short* Bx = (t < 8) ? (Wcombo + (size_t)p*1048576) : Wih_il;
    const unsigned short* ab[4]; const unsigned short* bb[4];
    #pragma unroll
    for (int q = 0; q < 4; ++q){
      ab[q] = (t < 8) ? (zin + ((size_t)nn[q]*8 + t)*512 + kc)
                      : (embb + (size_t)(node_base + nn[q])*512 + kc);
      int br = nbq*128 + q*32 + w*8 + (lane >> 3);
      bb[q] = Bx + (size_t)br*512 + kc;
    }
    KLOOP_BODY(ab, bb)
  }
  if (!first){ // H phase
    const unsigned short* ab[4]; const unsigned short* bb[4];
    #pragma unroll
    for (int q = 0; q < 4; ++q){
      ab[q] = hi + (size_t)nn[q]*512 + kc;
      int br = nbq*128 + q*32 + w*8 + (lane >> 3);
      bb[q] = Whh_il + (size_t)br*512 + kc;
    }
    KLOOP_BODY(ab, bb)
  }
  const int gate = r15 & 3;
  #pragma unroll
  for (int ni = 0; ni < 4; ++ni){
    int ci = nbq*128 + wn*64 + ni*16 + r15;
    float b = bsum[ci] + ((t < 8) ? bc[(size_t)p*2048 + ci] : 0.0f);
    #pragma unroll
    for (int mi = 0; mi < 4; ++mi){
      acc[mi][ni][0]+=b; acc[mi][ni][1]+=b; acc[mi][ni][2]+=b; acc[mi][ni][3]+=b;
    }
  }
  const int jr = r15 & 3;
  #pragma unroll
  for (int mi = 0; mi < 4; ++mi){
    int rl = mt*128 + wm*64 + mi*16 + g4*4 + jr;
    int n = pm ? pm[rl] : (rl < m ? rl : -1);
    #pragma unroll
    for (int ni = 0; ni < 4; ++ni){
      f32x4 a0 = acc[mi][ni];
      f32x4 a1 = shfl_xor4(a0, 1);
      f32x4 a2 = shfl_xor4(a0, 2);
      f32x4 a3 = shfl_xor4(a1, 2);
      f32x4 vi_ = sel4(a0,a1,a2,a3, gate);
      f32x4 vf_ = sel4(a0,a1,a2,a3, gate^1);
      f32x4 vg_ = sel4(a0,a1,a2,a3, gate^2);
      f32x4 vo_ = sel4(a0,a1,a2,a3, gate^3);
      float xi = pick4(vi_, jr), xf = pick4(vf_, jr);
      float xg = pick4(vg_, jr), xo = pick4(vo_, jr);
      if (n >= 0){
        int jz = nbq*32 + wn*16 + ni*4 + (r15 >> 2);
        size_t idx = (size_t)n*512 + jz;
        float i_ = sigm(xi), f_ = sigm(xf), g_ = tanh_(xg), o_ = sigm(xo);
        float cold = first ? 0.0f : cbuf[idx];
        float cn = fmaf(f_, cold, i_*g_);
        if (!last){ cbuf[idx] = cn; ho[idx] = f2bf(o_*tanh_(cn)); }
        else { if (l > 0) zo[idx] = f2bf(cn); else outp[idx] = cn; }
      }
    }
  }
}

// ---- launched step (levels 4): col-major jobs + XCD chunking ----
__global__ __launch_bounds__(256) void step_kernel(
    const unsigned short* __restrict__ embb,
    const unsigned short* __restrict__ Wcombo,
    const unsigned short* __restrict__ Wih_il,
    const unsigned short* __restrict__ Whh_il,
    const float* __restrict__ bsum, const float* __restrict__ bc,
    const unsigned short* __restrict__ zin, unsigned short* __restrict__ zo,
    const unsigned short* __restrict__ hi, unsigned short* __restrict__ ho,
    float* __restrict__ cbuf, float* __restrict__ outp,
    const int* __restrict__ perm_t, const int* __restrict__ tile_t,
    const int* __restrict__ meta_t,
    int fixed_nt, int MTcap, int node_base, int m, int t, int l)
{
  __shared__ unsigned short As[128*64];
  __shared__ unsigned short Bs[128*64];
  int ntiles = meta_t ? *meta_t : fixed_nt;
  if (ntiles > MTcap) ntiles = MTcap;
  const int njobs = ntiles * 16;
  const int chunk = (njobs + 7) >> 3;
  const int g = blockIdx.x & 7, i = blockIdx.x >> 3;
  const int job = g*chunk + i;
  if (i >= chunk || job >= njobs) return;
  const int mt = job % ntiles, nbq = job / ntiles;   // col-major: same nbq clusters per XCD
  step_core(As, Bs, embb, Wcombo, Wih_il, Whh_il, bsum, bc, zin, zo, hi, ho,
            cbuf, outp, perm_t, tile_t, node_base, m, t, mt, nbq, l);
}

// ---- persistent subtree kernel: levels 3..0, 36 phases, 192-block barrier ----
__global__ __launch_bounds__(256) void subtree_kernel(
    const unsigned short* __restrict__ embb,
    const unsigned short* __restrict__ Wcombo,
    const unsigned short* __restrict__ Wih_il,
    const unsigned short* __restrict__ Whh_il,
    const float* __restrict__ bsum, const float* __restrict__ bc,
    unsigned short* __restrict__ Z0, unsigned short* __restrict__ Z1,
    unsigned short* __restrict__ hA, unsigned short* __restrict__ hB,
    float* __restrict__ cbuf, float* __restrict__ outp,
    const int* __restrict__ perm, const int* __restrict__ tile_p,
    const int* __restrict__ meta, int* __restrict__ ctr)
{
  __shared__ unsigned short As[128*64];
  __shared__ unsigned short Bs[128*64];
  int k = 0;
  for (int l = 3; l >= 0; --l){
    const int m = 1 << (3*l);
    const int node_base = (m - 1) / 7;
    int MT, PB, TB;
    if (l == 3)      { MT = 12; PB = 40960; TB = 320; }
    else if (l == 2) { MT = 8;  PB = 53248; TB = 416; }
    else if (l == 1) { MT = 8;  PB = 61440; TB = 480; }
    else             { MT = 8;  PB = 69632; TB = 544; }
    const unsigned short* zin = (l & 1) ? Z1 : Z0;
    unsigned short* zo        = (l & 1) ? Z0 : Z1;
    for (int t = 0; t <= 8; ++t){
      const unsigned short* hi = (t & 1) ? hA : hB;
      unsigned short* ho       = (t & 1) ? hB : hA;
      int ntiles; const int* pm = nullptr; const int* tp = nullptr;
      if (t < 8){
        ntiles = meta[l*8 + t]; if (ntiles > MT) ntiles = MT;
        pm = perm + PB + t*MT*128;
        tp = tile_p + TB + t*MT;
      } else {
        ntiles = (m + 127) >> 7;
      }
      const int njobs = ntiles * 16;
      for (int job = blockIdx.x; job < njobs; job += 192){
        const int mt = job >> 4, nbq = job & 15;
        step_core(As, Bs, embb, Wcombo, Wih_il, Whh_il, bsum, bc, zin, zo, hi, ho,
                  cbuf, outp, pm, tp, node_base, m, t, mt, nbq, l);
      }
      ++k;
      if (!(l == 0 && t == 8)) gridbar(ctr, 192*k);
    }
  }
}

// OFF = {0, 1, 9, 73, 585, 4681, 37449}
extern "C" void kernel_launch(void* const* d_in, const int* in_sizes, int n_in,
                              void* d_out, int out_size, void* d_ws, size_t ws_size,
                              hipStream_t stream)
{
  (void)in_sizes; (void)n_in; (void)out_size; (void)ws_size;
  const float* emb   = (const float*)d_in[0];
  const int*   dep   = (const int*)  d_in[1];
  const float* W_dep = (const float*)d_in[2];
  const float* b_dep = (const float*)d_in[3];
  const float* W_ih  = (const float*)d_in[4];
  const float* W_hh  = (const float*)d_in[5];
  const float* b_ih  = (const float*)d_in[6];
  const float* b_hh  = (const float*)d_in[7];
  float* out = (float*)d_out;

  unsigned short* embb   = (unsigned short*)d_ws;                  // 37449*512
  unsigned short* Wih_il = embb   + 19173888ull;                   // 2048*512
  unsigned short* Whh_il = Wih_il + 1048576ull;                    // 2048*512
  unsigned short* Wleaf  = Whh_il + 1048576ull;                    // 1024*512
  unsigned short* WdT    = Wleaf  + 524288ull;                     // 8*512*512
  unsigned short* Wcombo = WdT    + 2097152ull;                    // 8*2048*512
  unsigned short* Z0     = Wcombo + 8388608ull;                    // 32768*512
  unsigned short* Z1     = Z0     + 16777216ull;                   // 4096*512
  unsigned short* hA     = Z1     + 2097152ull;                    // 4096*512
  unsigned short* hB     = hA     + 2097152ull;                    // 4096*512
  float* cbuf  = (float*)(hB + 2097152ull);                        // 4096*512 f32
  float* bsum  = cbuf + 2097152ull;                                // 2048
  float* bc    = bsum + 2048;                                      // 8*2048
  int*  perm   = (int*)(bc + 16384);                               // 77824
  int*  tile_p = perm + 77824;                                     // 608
  int*  meta   = tile_p + 608;                                     // 40
  int*  ctr    = meta + 40;                                        // 1

  prep_kernel<<<2929, 256, 0, stream>>>(emb, dep, W_dep, b_dep, W_ih, W_hh, b_ih, b_hh,
                                        embb, Wih_il, Whh_il, Wleaf, WdT, bsum, bc,
                                        perm, tile_p, meta, ctr);
  combo_gemm<<<512, 256, 0, stream>>>(Wih_il, WdT, Wcombo);
  leaf_gemm<<<2048, 256, 0, stream>>>(embb + (size_t)4681*512, Wleaf, bsum, Z0);

  // level 4: 9 launched steps (Z0 -> Z1)
  for (int t = 0; t <= 8; ++t){
    const unsigned short* hi = (t & 1) ? hA : hB;
    unsigned short* ho       = (t & 1) ? hB : hA;
    int grid = (t < 8) ? 40*16 : 32*16;
    step_kernel<<<grid, 256, 0, stream>>>(
        embb, Wcombo, Wih_il, Whh_il, bsum, bc,
        Z0, Z1, hi, ho, cbuf, nullptr,
        (t < 8) ? (perm + t*40*128) : nullptr,
        (t < 8) ? (tile_p + t*40) : nullptr,
        (t < 8) ? (meta + 4*8 + t) : nullptr,
        32, 40, 585, 4096, t, 4);
  }

  // levels 3..0: one persistent kernel, 36 phases, internal barrier
  subtree_kernel<<<192, 256, 0, stream>>>(embb, Wcombo, Wih_il, Whh_il, bsum, bc,
                                          Z0, Z1, hA, hB, cbuf, out,
                                          perm, tile_p, meta, ctr);
}

// Round 7
// 1538.733 us; speedup vs baseline: 1.8118x; 1.4255x over previous
//
#include <hip/hip_runtime.h>

typedef __attribute__((ext_vector_type(8))) short short8;
typedef __attribute__((ext_vector_type(4))) float f32x4;
typedef _Float16 half_t;

__device__ __forceinline__ unsigned short f2bf(float x){
  union { float f; unsigned u; } v; v.f = x;
  unsigned r = v.u + 0x7fffu + ((v.u >> 16) & 1u);
  return (unsigned short)(r >> 16);
}
__device__ __forceinline__ float sigm(float x){ return 1.0f / (1.0f + __expf(-x)); }
__device__ __forceinline__ float tanh_(float x){
  float e = __expf(2.0f * x);
  return 1.0f - 2.0f / (e + 1.0f);
}
__device__ __forceinline__ short8 load_bf8_f32(const float* p){
  float4 a = *(const float4*)p;
  float4 b = *(const float4*)(p + 4);
  short8 r;
  r[0]=(short)f2bf(a.x); r[1]=(short)f2bf(a.y); r[2]=(short)f2bf(a.z); r[3]=(short)f2bf(a.w);
  r[4]=(short)f2bf(b.x); r[5]=(short)f2bf(b.y); r[6]=(short)f2bf(b.z); r[7]=(short)f2bf(b.w);
  return r;
}
__device__ __forceinline__ f32x4 mfma16(short8 a, short8 b, f32x4 c){
  return __builtin_amdgcn_mfma_f32_16x16x32_bf16(a, b, c, 0, 0, 0);
}
__device__ __forceinline__ void gload16(const void* g, void* lds){
  __builtin_amdgcn_global_load_lds((const __attribute__((address_space(1))) void*)g,
                                   (__attribute__((address_space(3))) void*)lds, 16, 0, 0);
}
__device__ __forceinline__ f32x4 shfl_xor4(f32x4 v, int m){
  f32x4 r;
  r[0]=__shfl_xor(v[0],m); r[1]=__shfl_xor(v[1],m);
  r[2]=__shfl_xor(v[2],m); r[3]=__shfl_xor(v[3],m);
  return r;
}
__device__ __forceinline__ float pick4(f32x4 v, int k){
  float a = (k&1)? v[1] : v[0];
  float b = (k&1)? v[3] : v[2];
  return (k&2)? b : a;
}
__device__ __forceinline__ f32x4 sel4(f32x4 a0, f32x4 a1, f32x4 a2, f32x4 a3, int k){
  f32x4 x = (k&1)? a1 : a0;
  f32x4 y = (k&1)? a3 : a2;
  return (k&2)? y : x;
}

// ================= 128x128 MFMA GEMM K-loop (m97 structure) =================
#define KLOOP_BODY(ABASE, BBASE)                                                     \
  for (int kt = 0; kt < 8; ++kt){                                                    \
    _Pragma("unroll")                                                                \
    for (int q = 0; q < 4; ++q){                                                     \
      gload16(ABASE[q] + kt*64, &As[(q*32 + w*8)*64]);                               \
      gload16(BBASE[q] + kt*64, &Bs[(q*32 + w*8)*64]);                               \
    }                                                                                \
    __syncthreads();                                                                 \
    _Pragma("unroll")                                                                \
    for (int kk = 0; kk < 2; ++kk){                                                  \
      short8 av[4], bv[4];                                                           \
      _Pragma("unroll")                                                              \
      for (int i = 0; i < 4; ++i) av[i] = *(const short8*)&As[(wm*64 + i*16 + r15)*64 + kk*32 + g4*8]; \
      _Pragma("unroll")                                                              \
      for (int i = 0; i < 4; ++i) bv[i] = *(const short8*)&Bs[(wn*64 + i*16 + r15)*64 + kk*32 + g4*8]; \
      _Pragma("unroll")                                                              \
      for (int i = 0; i < 4; ++i)                                                    \
        _Pragma("unroll")                                                            \
        for (int j = 0; j < 4; ++j) acc[i][j] = mfma16(av[i], bv[j], acc[i][j]);     \
    }                                                                                \
    __syncthreads();                                                                 \
  }

// ---------------- prep: converts, remaps, transpose, bias folds, sorts ----------------
__global__ __launch_bounds__(256) void prep_kernel(
    const float* __restrict__ emb, const int* __restrict__ dep,
    const float* __restrict__ W_dep, const float* __restrict__ b_dep,
    const float* __restrict__ W_ih, const float* __restrict__ W_hh,
    const float* __restrict__ b_ih, const float* __restrict__ b_hh,
    unsigned short* __restrict__ embb, unsigned short* __restrict__ Wih_il,
    unsigned short* __restrict__ Whh_il, unsigned short* __restrict__ Wleaf,
    unsigned short* __restrict__ WdT, float* __restrict__ bsum, float* __restrict__ bc,
    int* __restrict__ perm, int* __restrict__ tile_p, int* __restrict__ meta)
{
  const int bid = blockIdx.x, tid = threadIdx.x;
  if (bid < 1024){
    for (size_t i = (size_t)bid*256 + tid; i < 2396736ull; i += 1024ull*256)
      *(short8*)(embb + i*8) = load_bf8_f32(emb + i*8);
  } else if (bid < 1536){
    int idx = (bid-1024)*256 + tid; int r = idx >> 6, c8 = idx & 63;
    int sr = (r & 3)*512 + (r >> 2);
    *(short8*)(Wih_il + (size_t)r*512 + c8*8) = load_bf8_f32(W_ih + (size_t)sr*512 + c8*8);
  } else if (bid < 2048){
    int idx = (bid-1536)*256 + tid; int r = idx >> 6, c8 = idx & 63;
    int sr = (r & 3)*512 + (r >> 2);
    *(short8*)(Whh_il + (size_t)r*512 + c8*8) = load_bf8_f32(W_hh + (size_t)sr*512 + c8*8);
  } else if (bid < 2304){
    int idx = (bid-2048)*256 + tid; int r = idx >> 6, c8 = idx & 63;
    int sr = ((r & 1) ? 2 : 0)*512 + (r >> 1);
    *(short8*)(Wleaf + (size_t)r*512 + c8*8) = load_bf8_f32(W_ih + (size_t)sr*512 + c8*8);
  } else if (bid < 2816){
    __shared__ unsigned short tle[64][65];
    int lb = bid - 2304; int p = lb >> 6; int tile = lb & 63;
    int i0 = (tile >> 3)*64, j0 = (tile & 7)*64;
    const float* src = W_dep + (size_t)p*512*512;
    for (int q = 0; q < 16; ++q){
      int e = q*256 + tid; int li = e >> 6, lj = e & 63;
      tle[li][lj] = f2bf(src[(size_t)(i0+li)*512 + (j0+lj)]);
    }
    __syncthreads();
    unsigned short* dst = WdT + (size_t)p*512*512;
    for (int q = 0; q < 16; ++q){
      int e = q*256 + tid; int lj = e >> 6, li = e & 63;
      dst[(size_t)(j0+lj)*512 + (i0+li)] = tle[li][lj];
    }
  } else if (bid < 2824){
    int r = (bid-2816)*256 + tid;
    if (r < 2048){ int g = r & 3, j = r >> 2; bsum[r] = b_ih[g*512+j] + b_hh[g*512+j]; }
  } else if (bid < 2888){
    __shared__ float bd[512];
    int lb = bid - 2824; int p = lb >> 3, ch = lb & 7;
    for (int i = tid; i < 512; i += 256) bd[i] = b_dep[p*512 + i];
    __syncthreads();
    int r = ch*256 + tid; int g = r & 3, j = r >> 2;
    const float* wr = W_ih + (size_t)(g*512 + j)*512;
    float s = 0.0f;
    for (int i = 0; i < 512; ++i) s = fmaf(wr[i], bd[i], s);
    bc[(size_t)p*2048 + r] = s;
  } else {
    __shared__ int cnt[8], base[8], fill[8];
    int lb = bid - 2888; const int l = lb >> 3, t = lb & 7;
    const int M_[5]  = {1,8,64,512,4096};
    const int CB_[5] = {1,9,73,585,4681};
    const int MT_[5] = {8,8,8,12,40};
    const int PB_[5] = {69632,61440,53248,40960,0};
    const int TB_[5] = {544,480,416,320,0};
    const int m = M_[l], cb = CB_[l], MT = MT_[l];
    int* pm = perm + PB_[l] + t*MT*128;
    int* tp = tile_p + TB_[l] + t*MT;
    if (tid < 8){ cnt[tid] = 0; fill[tid] = 0; }
    __syncthreads();
    for (int n = tid; n < m; n += 256) atomicAdd(&cnt[dep[cb + n*8 + t]], 1);
    __syncthreads();
    if (tid == 0){
      int tiles = 0;
      for (int p = 0; p < 8; ++p){
        base[p] = tiles*128;
        int g = (cnt[p] + 127) >> 7;
        for (int q = 0; q < g; ++q) tp[tiles + q] = p;
        tiles += g;
      }
      meta[l*8 + t] = tiles;
    }
    __syncthreads();
    for (int i = tid; i < MT*128; i += 256) pm[i] = -1;
    __syncthreads();
    for (int n = tid; n < m; n += 256){
      int p = dep[cb + n*8 + t];
      pm[base[p] + atomicAdd(&fill[p], 1)] = n;
    }
  }
}

// ---- one-time: Wcombo_il[p] = Wih_il @ W_dep[p]^T ----
__global__ __launch_bounds__(256) void combo_gemm(
    const unsigned short* __restrict__ A,
    const unsigned short* __restrict__ WdT,
    unsigned short* __restrict__ C)
{
  const int p  = blockIdx.x >> 6;
  const int mt = (blockIdx.x >> 2) & 15;
  const int nb = blockIdx.x & 3;
  __shared__ unsigned short As[128*64];
  __shared__ unsigned short Bs[128*64];
  const int tid = threadIdx.x, lane = tid & 63, w = tid >> 6;
  const int wm = w >> 1, wn = w & 1;
  const int r15 = lane & 15, g4 = lane >> 4;
  const int kc = (lane & 7)*8;

  const unsigned short* ab[4]; const unsigned short* bb[4];
  #pragma unroll
  for (int q = 0; q < 4; ++q){
    int rl = mt*128 + q*32 + w*8 + (lane >> 3);
    ab[q] = A + (size_t)rl*512 + kc;
    int br = nb*128 + q*32 + w*8 + (lane >> 3);
    bb[q] = WdT + (size_t)p*262144 + (size_t)br*512 + kc;
  }
  f32x4 acc[4][4] = {};
  KLOOP_BODY(ab, bb)
  unsigned short* Cp = C + (size_t)p*1048576;
  #pragma unroll
  for (int mi = 0; mi < 4; ++mi)
    #pragma unroll
    for (int ni = 0; ni < 4; ++ni)
      #pragma unroll
      for (int j = 0; j < 4; ++j){
        int row = mt*128 + wm*64 + mi*16 + g4*4 + j;
        int col = nb*128 + wn*64 + ni*16 + r15;
        Cp[(size_t)row*512 + col] = f2bf(acc[mi][ni][j]);
      }
}

// ---- leaf: z = sigm * tanh (2-gate interleaved B); col-major + XCD chunking ----
__global__ __launch_bounds__(256) void leaf_gemm(
    const unsigned short* __restrict__ embL,
    const unsigned short* __restrict__ Wleaf,
    const float* __restrict__ bsum,
    unsigned short* __restrict__ zo)
{
  const int nb = blockIdx.x & 7;
  const int mt = blockIdx.x >> 3;
  __shared__ unsigned short As[128*64];
  __shared__ unsigned short Bs[128*64];
  const int tid = threadIdx.x, lane = tid & 63, w = tid >> 6;
  const int wm = w >> 1, wn = w & 1;
  const int r15 = lane & 15, g4 = lane >> 4;
  const int kc = (lane & 7)*8;

  const unsigned short* ab[4]; const unsigned short* bb[4];
  #pragma unroll
  for (int q = 0; q < 4; ++q){
    int rl = mt*128 + q*32 + w*8 + (lane >> 3);
    ab[q] = embL + (size_t)rl*512 + kc;
    int br = nb*128 + q*32 + w*8 + (lane >> 3);
    bb[q] = Wleaf + (size_t)br*512 + kc;
  }
  f32x4 acc[4][4] = {};
  KLOOP_BODY(ab, bb)
  const int g2 = r15 & 1;
  #pragma unroll
  for (int ni = 0; ni < 4; ++ni){
    int ci = nb*128 + wn*64 + ni*16 + r15;
    float b = bsum[4*(ci >> 1) + (g2 ? 2 : 0)];
    #pragma unroll
    for (int mi = 0; mi < 4; ++mi){
      acc[mi][ni][0]+=b; acc[mi][ni][1]+=b; acc[mi][ni][2]+=b; acc[mi][ni][3]+=b;
    }
  }
  #pragma unroll
  for (int mi = 0; mi < 4; ++mi)
    #pragma unroll
    for (int ni = 0; ni < 4; ++ni){
      f32x4 a0 = acc[mi][ni];
      f32x4 a1 = shfl_xor4(a0, 1);
      f32x4 vi_ = g2 ? a1 : a0;
      f32x4 vg_ = g2 ? a0 : a1;
      int jz = (nb*128 + wn*64 + ni*16 + r15) >> 1;
      #pragma unroll
      for (int u = 0; u < 2; ++u){
        int jrow = (g2 << 1) + u;
        float zi = pick4(vi_, jrow), zg = pick4(vg_, jrow);
        int row = mt*128 + wm*64 + mi*16 + g4*4 + jrow;
        zo[(size_t)row*512 + jz] = f2bf(sigm(zi) * tanh_(zg));
      }
    }
}

// ---------------- fused recurrent step tile (level 4) ----------------
__device__ __forceinline__ void step_core(
    unsigned short* As, unsigned short* Bs,
    const unsigned short* __restrict__ embb,
    const unsigned short* __restrict__ Wcombo,
    const unsigned short* __restrict__ Wih_il,
    const unsigned short* __restrict__ Whh_il,
    const float* __restrict__ bsum, const float* __restrict__ bc,
    const unsigned short* __restrict__ zin, unsigned short* __restrict__ zo,
    const unsigned short* __restrict__ hi, unsigned short* __restrict__ ho,
    float* __restrict__ cbuf, float* __restrict__ outp,
    const int* __restrict__ pm, const int* __restrict__ tp,
    int node_base, int m, int t, int mt, int nbq, int l)
{
  const int tid = threadIdx.x, lane = tid & 63, w = tid >> 6;
  const int wm = w >> 1, wn = w & 1;
  const int r15 = lane & 15, g4 = lane >> 4;
  const int kc = (lane & 7)*8;
  const int first = (t == 0), last = (t == 8);
  const int p = tp ? tp[mt] : 0;

  int nn[4];
  #pragma unroll
  for (int q = 0; q < 4; ++q){
    int rl = mt*128 + q*32 + w*8 + (lane >> 3);
    int n = pm ? pm[rl] : (rl < m ? rl : -1);
    nn[q] = (n < 0) ? 0 : n;
  }
  f32x4 acc[4][4] = {};
  { // X phase
    const unsigned short* Bx = (t < 8) ? (Wcombo + (size_t)p*1048576) : Wih_il;
    const unsigned short* ab[4]; const unsigned short* bb[4];
    #pragma unroll
    for (int q = 0; q < 4; ++q){
      ab[q] = (t < 8) ? (zin + ((size_t)nn[q]*8 + t)*512 + kc)
                      : (embb + (size_t)(node_base + nn[q])*512 + kc);
      int br = nbq*128 + q*32 + w*8 + (lane >> 3);
      bb[q] = Bx + (size_t)br*512 + kc;
    }
    KLOOP_BODY(ab, bb)
  }
  if (!first){ // H phase
    const unsigned short* ab[4]; const unsigned short* bb[4];
    #pragma unroll
    for (int q = 0; q < 4; ++q){
      ab[q] = hi + (size_t)nn[q]*512 + kc;
      int br = nbq*128 + q*32 + w*8 + (lane >> 3);
      bb[q] = Whh_il + (size_t)br*512 + kc;
    }
    KLOOP_BODY(ab, bb)
  }
  const int gate = r15 & 3;
  #pragma unroll
  for (int ni = 0; ni < 4; ++ni){
    int ci = nbq*128 + wn*64 + ni*16 + r15;
    float b = bsum[ci] + ((t < 8) ? bc[(size_t)p*2048 + ci] : 0.0f);
    #pragma unroll
    for (int mi = 0; mi < 4; ++mi){
      acc[mi][ni][0]+=b; acc[mi][ni][1]+=b; acc[mi][ni][2]+=b; acc[mi][ni][3]+=b;
    }
  }
  const int jr = r15 & 3;
  #pragma unroll
  for (int mi = 0; mi < 4; ++mi){
    int rl = mt*128 + wm*64 + mi*16 + g4*4 + jr;
    int n = pm ? pm[rl] : (rl < m ? rl : -1);
    #pragma unroll
    for (int ni = 0; ni < 4; ++ni){
      f32x4 a0 = acc[mi][ni];
      f32x4 a1 = shfl_xor4(a0, 1);
      f32x4 a2 = shfl_xor4(a0, 2);
      f32x4 a3 = shfl_xor4(a1, 2);
      f32x4 vi_ = sel4(a0,a1,a2,a3, gate);
      f32x4 vf_ = sel4(a0,a1,a2,a3, gate^1);
      f32x4 vg_ = sel4(a0,a1,a2,a3, gate^2);
      f32x4 vo_ = sel4(a0,a1,a2,a3, gate^3);
      float xi = pick4(vi_, jr), xf = pick4(vf_, jr);
      float xg = pick4(vg_, jr), xo = pick4(vo_, jr);
      if (n >= 0){
        int jz = nbq*32 + wn*16 + ni*4 + (r15 >> 2);
        size_t idx = (size_t)n*512 + jz;
        float i_ = sigm(xi), f_ = sigm(xf), g_ = tanh_(xg), o_ = sigm(xo);
        float cold = first ? 0.0f : cbuf[idx];
        float cn = fmaf(f_, cold, i_*g_);
        if (!last){ cbuf[idx] = cn; ho[idx] = f2bf(o_*tanh_(cn)); }
        else { if (l > 0) zo[idx] = f2bf(cn); else outp[idx] = cn; }
      }
    }
  }
}

// ---- launched step (level 4): col-major jobs + XCD chunking ----
__global__ __launch_bounds__(256) void step_kernel(
    const unsigned short* __restrict__ embb,
    const unsigned short* __restrict__ Wcombo,
    const unsigned short* __restrict__ Wih_il,
    const unsigned short* __restrict__ Whh_il,
    const float* __restrict__ bsum, const float* __restrict__ bc,
    const unsigned short* __restrict__ zin, unsigned short* __restrict__ zo,
    const unsigned short* __restrict__ hi, unsigned short* __restrict__ ho,
    float* __restrict__ cbuf, float* __restrict__ outp,
    const int* __restrict__ perm_t, const int* __restrict__ tile_t,
    const int* __restrict__ meta_t,
    int fixed_nt, int MTcap, int node_base, int m, int t, int l)
{
  __shared__ unsigned short As[128*64];
  __shared__ unsigned short Bs[128*64];
  int ntiles = meta_t ? *meta_t : fixed_nt;
  if (ntiles > MTcap) ntiles = MTcap;
  const int njobs = ntiles * 16;
  const int chunk = (njobs + 7) >> 3;
  const int g = blockIdx.x & 7, i = blockIdx.x >> 3;
  const int job = g*chunk + i;
  if (i >= chunk || job >= njobs) return;
  const int mt = job % ntiles, nbq = job / ntiles;
  step_core(As, Bs, embb, Wcombo, Wih_il, Whh_il, bsum, bc, zin, zo, hi, ho,
            cbuf, outp, perm_t, tile_t, node_base, m, t, mt, nbq, l);
}

// ---- gatex: all X-gates for one level in one launch (t=0 fused pointwise) ----
// grid = (8*MT + mtiles8) * 16; jt tile-major, nbq = col-block
__global__ __launch_bounds__(256) void gatex_kernel(
    const unsigned short* __restrict__ embb,
    const unsigned short* __restrict__ Wcombo,
    const unsigned short* __restrict__ Wih_il,
    const float* __restrict__ bsum, const float* __restrict__ bc,
    const unsigned short* __restrict__ zin,
    half_t* __restrict__ gx, unsigned short* __restrict__ h0out,
    float* __restrict__ cbuf,
    const int* __restrict__ perm_l, const int* __restrict__ tile_l,
    const int* __restrict__ meta_l,
    int MT, int m, int node_base)
{
  __shared__ unsigned short As[128*64];
  __shared__ unsigned short Bs[128*64];
  const int jt = blockIdx.x >> 4, nbq = blockIdx.x & 15;
  int t, mt, p = 0;
  const int* pm = nullptr;
  if (jt < 8*MT){
    t = jt / MT; mt = jt - t*MT;
    if (mt >= meta_l[t]) return;
    pm = perm_l + t*MT*128;
    p = tile_l[t*MT + mt];
  } else {
    t = 8; mt = jt - 8*MT;
  }
  const int tid = threadIdx.x, lane = tid & 63, w = tid >> 6;
  const int wm = w >> 1, wn = w & 1;
  const int r15 = lane & 15, g4 = lane >> 4;
  const int kc = (lane & 7)*8;

  int nn[4];
  #pragma unroll
  for (int q = 0; q < 4; ++q){
    int rl = mt*128 + q*32 + w*8 + (lane >> 3);
    int n = pm ? pm[rl] : (rl < m ? rl : -1);
    nn[q] = (n < 0) ? 0 : n;
  }
  const unsigned short* Bx = (t < 8) ? (Wcombo + (size_t)p*1048576) : Wih_il;
  const unsigned short* ab[4]; const unsigned short* bb[4];
  #pragma unroll
  for (int q = 0; q < 4; ++q){
    ab[q] = (t < 8) ? (zin + ((size_t)nn[q]*8 + t)*512 + kc)
                    : (embb + (size_t)(node_base + nn[q])*512 + kc);
    int br = nbq*128 + q*32 + w*8 + (lane >> 3);
    bb[q] = Bx + (size_t)br*512 + kc;
  }
  f32x4 acc[4][4] = {};
  KLOOP_BODY(ab, bb)

  #pragma unroll
  for (int ni = 0; ni < 4; ++ni){
    int ci = nbq*128 + wn*64 + ni*16 + r15;
    float b = bsum[ci] + ((t < 8) ? bc[(size_t)p*2048 + ci] : 0.0f);
    #pragma unroll
    for (int mi = 0; mi < 4; ++mi){
      acc[mi][ni][0]+=b; acc[mi][ni][1]+=b; acc[mi][ni][2]+=b; acc[mi][ni][3]+=b;
    }
  }

  if (t == 0){
    // step-0 pointwise fused (h0=c0=0): c = i*g, h = o*tanh(c)
    const int gate = r15 & 3;
    const int jr = r15 & 3;
    #pragma unroll
    for (int mi = 0; mi < 4; ++mi){
      int rl = mt*128 + wm*64 + mi*16 + g4*4 + jr;
      int n = pm ? pm[rl] : (rl < m ? rl : -1);
      #pragma unroll
      for (int ni = 0; ni < 4; ++ni){
        f32x4 a0 = acc[mi][ni];
        f32x4 a1 = shfl_xor4(a0, 1);
        f32x4 a2 = shfl_xor4(a0, 2);
        f32x4 a3 = shfl_xor4(a1, 2);
        f32x4 vi_ = sel4(a0,a1,a2,a3, gate);
        f32x4 vg_ = sel4(a0,a1,a2,a3, gate^2);
        f32x4 vo_ = sel4(a0,a1,a2,a3, gate^3);
        float xi = pick4(vi_, jr);
        float xg = pick4(vg_, jr);
        float xo = pick4(vo_, jr);
        if (n >= 0){
          int jz = nbq*32 + wn*16 + ni*4 + (r15 >> 2);
          size_t idx = (size_t)n*512 + jz;
          float cn = sigm(xi) * tanh_(xg);
          cbuf[idx] = cn;
          h0out[idx] = f2bf(sigm(xo) * tanh_(cn));
        }
      }
    }
  } else {
    // store f16 gates (biases included) in IL-col layout
    #pragma unroll
    for (int mi = 0; mi < 4; ++mi)
      #pragma unroll
      for (int ni = 0; ni < 4; ++ni){
        int ci = nbq*128 + wn*64 + ni*16 + r15;
        #pragma unroll
        for (int j = 0; j < 4; ++j){
          int rl = mt*128 + wm*64 + mi*16 + g4*4 + j;
          int n = pm ? pm[rl] : (rl < m ? rl : -1);
          if (n >= 0) gx[((size_t)t*m + n)*2048 + ci] = (half_t)acc[mi][ni][j];
        }
      }
  }
}

// ---- hstep: H-GEMM only + gx add + pointwise (levels 3..0, t=1..8) ----
__global__ __launch_bounds__(256) void hstep_kernel(
    const unsigned short* __restrict__ Whh_il,
    const half_t* __restrict__ gx,
    const unsigned short* __restrict__ hi, unsigned short* __restrict__ ho,
    float* __restrict__ cbuf,
    unsigned short* __restrict__ zo, float* __restrict__ outp,
    int m, int t, int last)
{
  __shared__ unsigned short As[128*64];
  __shared__ unsigned short Bs[128*64];
  const int mt = blockIdx.x >> 4, nbq = blockIdx.x & 15;
  const int tid = threadIdx.x, lane = tid & 63, w = tid >> 6;
  const int wm = w >> 1, wn = w & 1;
  const int r15 = lane & 15, g4 = lane >> 4;
  const int kc = (lane & 7)*8;

  int nn[4];
  #pragma unroll
  for (int q = 0; q < 4; ++q){
    int rl = mt*128 + q*32 + w*8 + (lane >> 3);
    nn[q] = (rl < m) ? rl : 0;
  }
  const unsigned short* ab[4]; const unsigned short* bb[4];
  #pragma unroll
  for (int q = 0; q < 4; ++q){
    ab[q] = hi + (size_t)nn[q]*512 + kc;
    int br = nbq*128 + q*32 + w*8 + (lane >> 3);
    bb[q] = Whh_il + (size_t)br*512 + kc;
  }
  f32x4 acc[4][4] = {};
  KLOOP_BODY(ab, bb)

  // add precomputed X-gates (biases included)
  #pragma unroll
  for (int mi = 0; mi < 4; ++mi)
    #pragma unroll
    for (int ni = 0; ni < 4; ++ni){
      int ci = nbq*128 + wn*64 + ni*16 + r15;
      #pragma unroll
      for (int j = 0; j < 4; ++j){
        int rl = mt*128 + wm*64 + mi*16 + g4*4 + j;
        if (rl < m) acc[mi][ni][j] += (float)gx[((size_t)t*m + rl)*2048 + ci];
      }
    }

  const int gate = r15 & 3;
  const int jr = r15 & 3;
  #pragma unroll
  for (int mi = 0; mi < 4; ++mi){
    int rl = mt*128 + wm*64 + mi*16 + g4*4 + jr;
    int n = (rl < m) ? rl : -1;
    #pragma unroll
    for (int ni = 0; ni < 4; ++ni){
      f32x4 a0 = acc[mi][ni];
      f32x4 a1 = shfl_xor4(a0, 1);
      f32x4 a2 = shfl_xor4(a0, 2);
      f32x4 a3 = shfl_xor4(a1, 2);
      f32x4 vi_ = sel4(a0,a1,a2,a3, gate);
      f32x4 vf_ = sel4(a0,a1,a2,a3, gate^1);
      f32x4 vg_ = sel4(a0,a1,a2,a3, gate^2);
      f32x4 vo_ = sel4(a0,a1,a2,a3, gate^3);
      float xi = pick4(vi_, jr), xf = pick4(vf_, jr);
      float xg = pick4(vg_, jr), xo = pick4(vo_, jr);
      if (n >= 0){
        int jz = nbq*32 + wn*16 + ni*4 + (r15 >> 2);
        size_t idx = (size_t)n*512 + jz;
        float i_ = sigm(xi), f_ = sigm(xf), g_ = tanh_(xg), o_ = sigm(xo);
        float cn = fmaf(f_, cbuf[idx], i_*g_);
        if (!last){ cbuf[idx] = cn; ho[idx] = f2bf(o_*tanh_(cn)); }
        else { if (zo) zo[idx] = f2bf(cn); else outp[idx] = cn; }
      }
    }
  }
}

// OFF = {0, 1, 9, 73, 585, 4681, 37449}
extern "C" void kernel_launch(void* const* d_in, const int* in_sizes, int n_in,
                              void* d_out, int out_size, void* d_ws, size_t ws_size,
                              hipStream_t stream)
{
  (void)in_sizes; (void)n_in; (void)out_size; (void)ws_size;
  const float* emb   = (const float*)d_in[0];
  const int*   dep   = (const int*)  d_in[1];
  const float* W_dep = (const float*)d_in[2];
  const float* b_dep = (const float*)d_in[3];
  const float* W_ih  = (const float*)d_in[4];
  const float* W_hh  = (const float*)d_in[5];
  const float* b_ih  = (const float*)d_in[6];
  const float* b_hh  = (const float*)d_in[7];
  float* out = (float*)d_out;

  unsigned short* embb   = (unsigned short*)d_ws;                  // 37449*512
  unsigned short* Wih_il = embb   + 19173888ull;                   // 2048*512
  unsigned short* Whh_il = Wih_il + 1048576ull;                    // 2048*512
  unsigned short* Wleaf  = Whh_il + 1048576ull;                    // 1024*512
  unsigned short* WdT    = Wleaf  + 524288ull;                     // 8*512*512
  unsigned short* Wcombo = WdT    + 2097152ull;                    // 8*2048*512
  unsigned short* Z0     = Wcombo + 8388608ull;                    // 32768*512
  unsigned short* Z1     = Z0     + 16777216ull;                   // 4096*512
  unsigned short* hA     = Z1     + 2097152ull;                    // 4096*512
  unsigned short* hB     = hA     + 2097152ull;                    // 4096*512
  float* cbuf  = (float*)(hB + 2097152ull);                        // 4096*512 f32
  float* bsum  = cbuf + 2097152ull;                                // 2048
  float* bc    = bsum + 2048;                                      // 8*2048
  int*  perm   = (int*)(bc + 16384);                               // 77824
  int*  tile_p = perm + 77824;                                     // 608
  int*  meta   = tile_p + 608;                                     // 40
  half_t* gx   = (half_t*)(meta + 40);                             // 9*512*2048 f16

  prep_kernel<<<2928, 256, 0, stream>>>(emb, dep, W_dep, b_dep, W_ih, W_hh, b_ih, b_hh,
                                        embb, Wih_il, Whh_il, Wleaf, WdT, bsum, bc,
                                        perm, tile_p, meta);
  combo_gemm<<<512, 256, 0, stream>>>(Wih_il, WdT, Wcombo);
  leaf_gemm<<<2048, 256, 0, stream>>>(embb + (size_t)4681*512, Wleaf, bsum, Z0);

  // level 4: 9 fused launched steps (Z0 -> Z1)
  for (int t = 0; t <= 8; ++t){
    const unsigned short* hi = (t & 1) ? hA : hB;
    unsigned short* ho       = (t & 1) ? hB : hA;
    int grid = (t < 8) ? 40*16 : 32*16;
    step_kernel<<<grid, 256, 0, stream>>>(
        embb, Wcombo, Wih_il, Whh_il, bsum, bc,
        Z0, Z1, hi, ho, cbuf, nullptr,
        (t < 8) ? (perm + t*40*128) : nullptr,
        (t < 8) ? (tile_p + t*40) : nullptr,
        (t < 8) ? (meta + 4*8 + t) : nullptr,
        32, 40, 585, 4096, t, 4);
  }

  // levels 3..0: per level, one wide gatex launch + 8 sequential H-only steps
  struct LvP { int m, MT, PB, TB, nb_, mtiles; };
  const LvP LP[4] = {
    {512, 12, 40960, 320, 73, 4},   // l=3
    {64,  8,  53248, 416, 9,  1},   // l=2
    {8,   8,  61440, 480, 1,  1},   // l=1
    {1,   8,  69632, 544, 0,  1}};  // l=0
  for (int k = 0; k < 4; ++k){
    const int l = 3 - k;
    const unsigned short* zin = (l & 1) ? Z1 : Z0;
    unsigned short* zo        = (l & 1) ? Z0 : Z1;
    gatex_kernel<<<(8*LP[k].MT + LP[k].mtiles)*16, 256, 0, stream>>>(
        embb, Wcombo, Wih_il, bsum, bc, zin, gx, hA, cbuf,
        perm + LP[k].PB, tile_p + LP[k].TB, meta + l*8,
        LP[k].MT, LP[k].m, LP[k].nb_);
    for (int t = 1; t <= 8; ++t){
      const unsigned short* hi = (t & 1) ? hA : hB;
      unsigned short* ho       = (t & 1) ? hB : hA;
      hstep_kernel<<<LP[k].mtiles*16, 256, 0, stream>>>(
          Whh_il, gx, hi, ho, cbuf,
          (l > 0) ? zo : nullptr, (l == 0) ? out : nullptr,
          LP[k].m, t, (t == 8));
    }
  }
}

// Round 8
// 1381.457 us; speedup vs baseline: 2.0181x; 1.1138x over previous
//
#include <hip/hip_runtime.h>

typedef __attribute__((ext_vector_type(8))) short short8;
typedef __attribute__((ext_vector_type(4))) float f32x4;
typedef _Float16 half_t;

__device__ __forceinline__ unsigned short f2bf(float x){
  union { float f; unsigned u; } v; v.f = x;
  unsigned r = v.u + 0x7fffu + ((v.u >> 16) & 1u);
  return (unsigned short)(r >> 16);
}
__device__ __forceinline__ float sigm(float x){ return 1.0f / (1.0f + __expf(-x)); }
__device__ __forceinline__ float tanh_(float x){
  float e = __expf(2.0f * x);
  return 1.0f - 2.0f / (e + 1.0f);
}
__device__ __forceinline__ short8 load_bf8_f32(const float* p){
  float4 a = *(const float4*)p;
  float4 b = *(const float4*)(p + 4);
  short8 r;
  r[0]=(short)f2bf(a.x); r[1]=(short)f2bf(a.y); r[2]=(short)f2bf(a.z); r[3]=(short)f2bf(a.w);
  r[4]=(short)f2bf(b.x); r[5]=(short)f2bf(b.y); r[6]=(short)f2bf(b.z); r[7]=(short)f2bf(b.w);
  return r;
}
__device__ __forceinline__ f32x4 mfma16(short8 a, short8 b, f32x4 c){
  return __builtin_amdgcn_mfma_f32_16x16x32_bf16(a, b, c, 0, 0, 0);
}
__device__ __forceinline__ void gload16(const void* g, void* lds){
  __builtin_amdgcn_global_load_lds((const __attribute__((address_space(1))) void*)g,
                                   (__attribute__((address_space(3))) void*)lds, 16, 0, 0);
}
__device__ __forceinline__ f32x4 shfl_xor4(f32x4 v, int m){
  f32x4 r;
  r[0]=__shfl_xor(v[0],m); r[1]=__shfl_xor(v[1],m);
  r[2]=__shfl_xor(v[2],m); r[3]=__shfl_xor(v[3],m);
  return r;
}
__device__ __forceinline__ float pick4(f32x4 v, int k){
  float a = (k&1)? v[1] : v[0];
  float b = (k&1)? v[3] : v[2];
  return (k&2)? b : a;
}
__device__ __forceinline__ f32x4 sel4(f32x4 a0, f32x4 a1, f32x4 a2, f32x4 a3, int k){
  f32x4 x = (k&1)? a1 : a0;
  f32x4 y = (k&1)? a3 : a2;
  return (k&2)? y : x;
}

// ======= 128x128 MFMA GEMM K-loop: 2-phase double-buffer + XOR bank swizzle =======
// LDS layout: linear dest (global_load_lds), SOURCE column pre-swizzled by
// (lane>>3 == row&7); ds_read applies the same XOR -> identical elements, no
// 16-way bank conflicts (16 lanes spread over 8 distinct 16B slots).
// kc in each kernel must be: ((lane & 7) ^ (lane >> 3)) * 8
#define KLOOP_BODY(ABASE, BBASE)                                                     \
  {                                                                                  \
    _Pragma("unroll")                                                                \
    for (int q = 0; q < 4; ++q){                                                     \
      gload16(ABASE[q], As + (q*32 + w*8)*64);                                       \
      gload16(BBASE[q], Bs + (q*32 + w*8)*64);                                       \
    }                                                                                \
    __syncthreads();                                                                 \
    for (int kt = 0; kt < 8; ++kt){                                                  \
      unsigned short* Ac = As + (kt & 1)*8192;                                       \
      unsigned short* Bc = Bs + (kt & 1)*8192;                                       \
      if (kt < 7){                                                                   \
        unsigned short* An = As + ((kt + 1) & 1)*8192;                               \
        unsigned short* Bn = Bs + ((kt + 1) & 1)*8192;                               \
        _Pragma("unroll")                                                            \
        for (int q = 0; q < 4; ++q){                                                 \
          gload16(ABASE[q] + (kt+1)*64, An + (q*32 + w*8)*64);                       \
          gload16(BBASE[q] + (kt+1)*64, Bn + (q*32 + w*8)*64);                       \
        }                                                                            \
      }                                                                              \
      _Pragma("unroll")                                                              \
      for (int kk = 0; kk < 2; ++kk){                                                \
        short8 av[4], bv[4];                                                         \
        _Pragma("unroll")                                                            \
        for (int i = 0; i < 4; ++i)                                                  \
          av[i] = *(const short8*)&Ac[(wm*64 + i*16 + r15)*64 + (((kk*4 + g4) ^ (r15 & 7))*8)]; \
        _Pragma("unroll")                                                            \
        for (int i = 0; i < 4; ++i)                                                  \
          bv[i] = *(const short8*)&Bc[(wn*64 + i*16 + r15)*64 + (((kk*4 + g4) ^ (r15 & 7))*8)]; \
        _Pragma("unroll")                                                            \
        for (int i = 0; i < 4; ++i)                                                  \
          _Pragma("unroll")                                                          \
          for (int j = 0; j < 4; ++j) acc[i][j] = mfma16(av[i], bv[j], acc[i][j]);   \
      }                                                                              \
      __syncthreads();                                                               \
    }                                                                                \
  }

// ---------------- prep: converts, remaps, transpose, bias folds, sorts ----------------
__global__ __launch_bounds__(256) void prep_kernel(
    const float* __restrict__ emb, const int* __restrict__ dep,
    const float* __restrict__ W_dep, const float* __restrict__ b_dep,
    const float* __restrict__ W_ih, const float* __restrict__ W_hh,
    const float* __restrict__ b_ih, const float* __restrict__ b_hh,
    unsigned short* __restrict__ embb, unsigned short* __restrict__ Wih_il,
    unsigned short* __restrict__ Whh_il, unsigned short* __restrict__ Wleaf,
    unsigned short* __restrict__ WdT, float* __restrict__ bsum, float* __restrict__ bc,
    int* __restrict__ perm, int* __restrict__ tile_p, int* __restrict__ meta)
{
  const int bid = blockIdx.x, tid = threadIdx.x;
  if (bid < 1024){
    for (size_t i = (size_t)bid*256 + tid; i < 2396736ull; i += 1024ull*256)
      *(short8*)(embb + i*8) = load_bf8_f32(emb + i*8);
  } else if (bid < 1536){
    int idx = (bid-1024)*256 + tid; int r = idx >> 6, c8 = idx & 63;
    int sr = (r & 3)*512 + (r >> 2);
    *(short8*)(Wih_il + (size_t)r*512 + c8*8) = load_bf8_f32(W_ih + (size_t)sr*512 + c8*8);
  } else if (bid < 2048){
    int idx = (bid-1536)*256 + tid; int r = idx >> 6, c8 = idx & 63;
    int sr = (r & 3)*512 + (r >> 2);
    *(short8*)(Whh_il + (size_t)r*512 + c8*8) = load_bf8_f32(W_hh + (size_t)sr*512 + c8*8);
  } else if (bid < 2304){
    int idx = (bid-2048)*256 + tid; int r = idx >> 6, c8 = idx & 63;
    int sr = ((r & 1) ? 2 : 0)*512 + (r >> 1);
    *(short8*)(Wleaf + (size_t)r*512 + c8*8) = load_bf8_f32(W_ih + (size_t)sr*512 + c8*8);
  } else if (bid < 2816){
    __shared__ unsigned short tle[64][65];
    int lb = bid - 2304; int p = lb >> 6; int tile = lb & 63;
    int i0 = (tile >> 3)*64, j0 = (tile & 7)*64;
    const float* src = W_dep + (size_t)p*512*512;
    for (int q = 0; q < 16; ++q){
      int e = q*256 + tid; int li = e >> 6, lj = e & 63;
      tle[li][lj] = f2bf(src[(size_t)(i0+li)*512 + (j0+lj)]);
    }
    __syncthreads();
    unsigned short* dst = WdT + (size_t)p*512*512;
    for (int q = 0; q < 16; ++q){
      int e = q*256 + tid; int lj = e >> 6, li = e & 63;
      dst[(size_t)(j0+lj)*512 + (i0+li)] = tle[li][lj];
    }
  } else if (bid < 2824){
    int r = (bid-2816)*256 + tid;
    if (r < 2048){ int g = r & 3, j = r >> 2; bsum[r] = b_ih[g*512+j] + b_hh[g*512+j]; }
  } else if (bid < 2888){
    __shared__ float bd[512];
    int lb = bid - 2824; int p = lb >> 3, ch = lb & 7;
    for (int i = tid; i < 512; i += 256) bd[i] = b_dep[p*512 + i];
    __syncthreads();
    int r = ch*256 + tid; int g = r & 3, j = r >> 2;
    const float* wr = W_ih + (size_t)(g*512 + j)*512;
    float s = 0.0f;
    for (int i = 0; i < 512; ++i) s = fmaf(wr[i], bd[i], s);
    bc[(size_t)p*2048 + r] = s;
  } else {
    __shared__ int cnt[8], base[8], fill[8];
    int lb = bid - 2888; const int l = lb >> 3, t = lb & 7;
    const int M_[5]  = {1,8,64,512,4096};
    const int CB_[5] = {1,9,73,585,4681};
    const int MT_[5] = {8,8,8,12,40};
    const int PB_[5] = {69632,61440,53248,40960,0};
    const int TB_[5] = {544,480,416,320,0};
    const int m = M_[l], cb = CB_[l], MT = MT_[l];
    int* pm = perm + PB_[l] + t*MT*128;
    int* tp = tile_p + TB_[l] + t*MT;
    if (tid < 8){ cnt[tid] = 0; fill[tid] = 0; }
    __syncthreads();
    for (int n = tid; n < m; n += 256) atomicAdd(&cnt[dep[cb + n*8 + t]], 1);
    __syncthreads();
    if (tid == 0){
      int tiles = 0;
      for (int p = 0; p < 8; ++p){
        base[p] = tiles*128;
        int g = (cnt[p] + 127) >> 7;
        for (int q = 0; q < g; ++q) tp[tiles + q] = p;
        tiles += g;
      }
      meta[l*8 + t] = tiles;
    }
    __syncthreads();
    for (int i = tid; i < MT*128; i += 256) pm[i] = -1;
    __syncthreads();
    for (int n = tid; n < m; n += 256){
      int p = dep[cb + n*8 + t];
      pm[base[p] + atomicAdd(&fill[p], 1)] = n;
    }
  }
}

// ---- one-time: Wcombo_il[p] = Wih_il @ W_dep[p]^T ----
__global__ __launch_bounds__(256) void combo_gemm(
    const unsigned short* __restrict__ A,
    const unsigned short* __restrict__ WdT,
    unsigned short* __restrict__ C)
{
  const int p  = blockIdx.x >> 6;
  const int mt = (blockIdx.x >> 2) & 15;
  const int nb = blockIdx.x & 3;
  __shared__ unsigned short As[16384];
  __shared__ unsigned short Bs[16384];
  const int tid = threadIdx.x, lane = tid & 63, w = tid >> 6;
  const int wm = w >> 1, wn = w & 1;
  const int r15 = lane & 15, g4 = lane >> 4;
  const int kc = ((lane & 7) ^ (lane >> 3)) * 8;

  const unsigned short* ab[4]; const unsigned short* bb[4];
  #pragma unroll
  for (int q = 0; q < 4; ++q){
    int rl = mt*128 + q*32 + w*8 + (lane >> 3);
    ab[q] = A + (size_t)rl*512 + kc;
    int br = nb*128 + q*32 + w*8 + (lane >> 3);
    bb[q] = WdT + (size_t)p*262144 + (size_t)br*512 + kc;
  }
  f32x4 acc[4][4] = {};
  KLOOP_BODY(ab, bb)
  unsigned short* Cp = C + (size_t)p*1048576;
  #pragma unroll
  for (int mi = 0; mi < 4; ++mi)
    #pragma unroll
    for (int ni = 0; ni < 4; ++ni)
      #pragma unroll
      for (int j = 0; j < 4; ++j){
        int row = mt*128 + wm*64 + mi*16 + g4*4 + j;
        int col = nb*128 + wn*64 + ni*16 + r15;
        Cp[(size_t)row*512 + col] = f2bf(acc[mi][ni][j]);
      }
}

// ---- leaf: z = sigm * tanh (2-gate interleaved B) ----
__global__ __launch_bounds__(256) void leaf_gemm(
    const unsigned short* __restrict__ embL,
    const unsigned short* __restrict__ Wleaf,
    const float* __restrict__ bsum,
    unsigned short* __restrict__ zo)
{
  const int nb = blockIdx.x & 7;
  const int mt = blockIdx.x >> 3;
  __shared__ unsigned short As[16384];
  __shared__ unsigned short Bs[16384];
  const int tid = threadIdx.x, lane = tid & 63, w = tid >> 6;
  const int wm = w >> 1, wn = w & 1;
  const int r15 = lane & 15, g4 = lane >> 4;
  const int kc = ((lane & 7) ^ (lane >> 3)) * 8;

  const unsigned short* ab[4]; const unsigned short* bb[4];
  #pragma unroll
  for (int q = 0; q < 4; ++q){
    int rl = mt*128 + q*32 + w*8 + (lane >> 3);
    ab[q] = embL + (size_t)rl*512 + kc;
    int br = nb*128 + q*32 + w*8 + (lane >> 3);
    bb[q] = Wleaf + (size_t)br*512 + kc;
  }
  f32x4 acc[4][4] = {};
  KLOOP_BODY(ab, bb)
  const int g2 = r15 & 1;
  #pragma unroll
  for (int ni = 0; ni < 4; ++ni){
    int ci = nb*128 + wn*64 + ni*16 + r15;
    float b = bsum[4*(ci >> 1) + (g2 ? 2 : 0)];
    #pragma unroll
    for (int mi = 0; mi < 4; ++mi){
      acc[mi][ni][0]+=b; acc[mi][ni][1]+=b; acc[mi][ni][2]+=b; acc[mi][ni][3]+=b;
    }
  }
  #pragma unroll
  for (int mi = 0; mi < 4; ++mi)
    #pragma unroll
    for (int ni = 0; ni < 4; ++ni){
      f32x4 a0 = acc[mi][ni];
      f32x4 a1 = shfl_xor4(a0, 1);
      f32x4 vi_ = g2 ? a1 : a0;
      f32x4 vg_ = g2 ? a0 : a1;
      int jz = (nb*128 + wn*64 + ni*16 + r15) >> 1;
      #pragma unroll
      for (int u = 0; u < 2; ++u){
        int jrow = (g2 << 1) + u;
        float zi = pick4(vi_, jrow), zg = pick4(vg_, jrow);
        int row = mt*128 + wm*64 + mi*16 + g4*4 + jrow;
        zo[(size_t)row*512 + jz] = f2bf(sigm(zi) * tanh_(zg));
      }
    }
}

// ---------------- fused recurrent step tile (level 4) ----------------
__device__ __forceinline__ void step_core(
    unsigned short* As, unsigned short* Bs,
    const unsigned short* __restrict__ embb,
    const unsigned short* __restrict__ Wcombo,
    const unsigned short* __restrict__ Wih_il,
    const unsigned short* __restrict__ Whh_il,
    const float* __restrict__ bsum, const float* __restrict__ bc,
    const unsigned short* __restrict__ zin, unsigned short* __restrict__ zo,
    const unsigned short* __restrict__ hi, unsigned short* __restrict__ ho,
    float* __restrict__ cbuf, float* __restrict__ outp,
    const int* __restrict__ pm, const int* __restrict__ tp,
    int node_base, int m, int t, int mt, int nbq, int l)
{
  const int tid = threadIdx.x, lane = tid & 63, w = tid >> 6;
  const int wm = w >> 1, wn = w & 1;
  const int r15 = lane & 15, g4 = lane >> 4;
  const int kc = ((lane & 7) ^ (lane >> 3)) * 8;
  const int first = (t == 0), last = (t == 8);
  const int p = tp ? tp[mt] : 0;

  int nn[4];
  #pragma unroll
  for (int q = 0; q < 4; ++q){
    int rl = mt*128 + q*32 + w*8 + (lane >> 3);
    int n = pm ? pm[rl] : (rl < m ? rl : -1);
    nn[q] = (n < 0) ? 0 : n;
  }
  f32x4 acc[4][4] = {};
  { // X phase
    const unsigned short* Bx = (t < 8) ? (Wcombo + (size_t)p*1048576) : Wih_il;
    const unsigned short* ab[4]; const unsigned short* bb[4];
    #pragma unroll
    for (int q = 0; q < 4; ++q){
      ab[q] = (t < 8) ? (zin + ((size_t)nn[q]*8 + t)*512 + kc)
                      : (embb + (size_t)(node_base + nn[q])*512 + kc);
      int br = nbq*128 + q*32 + w*8 + (lane >> 3);
      bb[q] = Bx + (size_t)br*512 + kc;
    }
    KLOOP_BODY(ab, bb)
  }
  if (!first){ // H phase
    const unsigned short* ab[4]; const unsigned short* bb[4];
    #pragma unroll
    for (int q = 0; q < 4; ++q){
      ab[q] = hi + (size_t)nn[q]*512 + kc;
      int br = nbq*128 + q*32 + w*8 + (lane >> 3);
      bb[q] = Whh_il + (size_t)br*512 + kc;
    }
    KLOOP_BODY(ab, bb)
  }
  const int gate = r15 & 3;
  #pragma unroll
  for (int ni = 0; ni < 4; ++ni){
    int ci = nbq*128 + wn*64 + ni*16 + r15;
    float b = bsum[ci] + ((t < 8) ? bc[(size_t)p*2048 + ci] : 0.0f);
    #pragma unroll
    for (int mi = 0; mi < 4; ++mi){
      acc[mi][ni][0]+=b; acc[mi][ni][1]+=b; acc[mi][ni][2]+=b; acc[mi][ni][3]+=b;
    }
  }
  const int jr = r15 & 3;
  #pragma unroll
  for (int mi = 0; mi < 4; ++mi){
    int rl = mt*128 + wm*64 + mi*16 + g4*4 + jr;
    int n = pm ? pm[rl] : (rl < m ? rl : -1);
    #pragma unroll
    for (int ni = 0; ni < 4; ++ni){
      f32x4 a0 = acc[mi][ni];
      f32x4 a1 = shfl_xor4(a0, 1);
      f32x4 a2 = shfl_xor4(a0, 2);
      f32x4 a3 = shfl_xor4(a1, 2);
      f32x4 vi_ = sel4(a0,a1,a2,a3, gate);
      f32x4 vf_ = sel4(a0,a1,a2,a3, gate^1);
      f32x4 vg_ = sel4(a0,a1,a2,a3, gate^2);
      f32x4 vo_ = sel4(a0,a1,a2,a3, gate^3);
      float xi = pick4(vi_, jr), xf = pick4(vf_, jr);
      float xg = pick4(vg_, jr), xo = pick4(vo_, jr);
      if (n >= 0){
        int jz = nbq*32 + wn*16 + ni*4 + (r15 >> 2);
        size_t idx = (size_t)n*512 + jz;
        float i_ = sigm(xi), f_ = sigm(xf), g_ = tanh_(xg), o_ = sigm(xo);
        float cold = first ? 0.0f : cbuf[idx];
        float cn = fmaf(f_, cold, i_*g_);
        if (!last){ cbuf[idx] = cn; ho[idx] = f2bf(o_*tanh_(cn)); }
        else { if (l > 0) zo[idx] = f2bf(cn); else outp[idx] = cn; }
      }
    }
  }
}

// ---- launched step (level 4): col-major jobs + XCD chunking ----
__global__ __launch_bounds__(256) void step_kernel(
    const unsigned short* __restrict__ embb,
    const unsigned short* __restrict__ Wcombo,
    const unsigned short* __restrict__ Wih_il,
    const unsigned short* __restrict__ Whh_il,
    const float* __restrict__ bsum, const float* __restrict__ bc,
    const unsigned short* __restrict__ zin, unsigned short* __restrict__ zo,
    const unsigned short* __restrict__ hi, unsigned short* __restrict__ ho,
    float* __restrict__ cbuf, float* __restrict__ outp,
    const int* __restrict__ perm_t, const int* __restrict__ tile_t,
    const int* __restrict__ meta_t,
    int fixed_nt, int MTcap, int node_base, int m, int t, int l)
{
  __shared__ unsigned short As[16384];
  __shared__ unsigned short Bs[16384];
  int ntiles = meta_t ? *meta_t : fixed_nt;
  if (ntiles > MTcap) ntiles = MTcap;
  const int njobs = ntiles * 16;
  const int chunk = (njobs + 7) >> 3;
  const int g = blockIdx.x & 7, i = blockIdx.x >> 3;
  const int job = g*chunk + i;
  if (i >= chunk || job >= njobs) return;
  const int mt = job % ntiles, nbq = job / ntiles;
  step_core(As, Bs, embb, Wcombo, Wih_il, Whh_il, bsum, bc, zin, zo, hi, ho,
            cbuf, outp, perm_t, tile_t, node_base, m, t, mt, nbq, l);
}

// ---- gatex: all X-gates for one level in one launch (t=0 fused pointwise) ----
__global__ __launch_bounds__(256) void gatex_kernel(
    const unsigned short* __restrict__ embb,
    const unsigned short* __restrict__ Wcombo,
    const unsigned short* __restrict__ Wih_il,
    const float* __restrict__ bsum, const float* __restrict__ bc,
    const unsigned short* __restrict__ zin,
    half_t* __restrict__ gx, unsigned short* __restrict__ h0out,
    float* __restrict__ cbuf,
    const int* __restrict__ perm_l, const int* __restrict__ tile_l,
    const int* __restrict__ meta_l,
    int MT, int m, int node_base)
{
  __shared__ unsigned short As[16384];
  __shared__ unsigned short Bs[16384];
  const int jt = blockIdx.x >> 4, nbq = blockIdx.x & 15;
  int t, mt, p = 0;
  const int* pm = nullptr;
  if (jt < 8*MT){
    t = jt / MT; mt = jt - t*MT;
    if (mt >= meta_l[t]) return;
    pm = perm_l + t*MT*128;
    p = tile_l[t*MT + mt];
  } else {
    t = 8; mt = jt - 8*MT;
  }
  const int tid = threadIdx.x, lane = tid & 63, w = tid >> 6;
  const int wm = w >> 1, wn = w & 1;
  const int r15 = lane & 15, g4 = lane >> 4;
  const int kc = ((lane & 7) ^ (lane >> 3)) * 8;

  int nn[4];
  #pragma unroll
  for (int q = 0; q < 4; ++q){
    int rl = mt*128 + q*32 + w*8 + (lane >> 3);
    int n = pm ? pm[rl] : (rl < m ? rl : -1);
    nn[q] = (n < 0) ? 0 : n;
  }
  const unsigned short* Bx = (t < 8) ? (Wcombo + (size_t)p*1048576) : Wih_il;
  const unsigned short* ab[4]; const unsigned short* bb[4];
  #pragma unroll
  for (int q = 0; q < 4; ++q){
    ab[q] = (t < 8) ? (zin + ((size_t)nn[q]*8 + t)*512 + kc)
                    : (embb + (size_t)(node_base + nn[q])*512 + kc);
    int br = nbq*128 + q*32 + w*8 + (lane >> 3);
    bb[q] = Bx + (size_t)br*512 + kc;
  }
  f32x4 acc[4][4] = {};
  KLOOP_BODY(ab, bb)

  #pragma unroll
  for (int ni = 0; ni < 4; ++ni){
    int ci = nbq*128 + wn*64 + ni*16 + r15;
    float b = bsum[ci] + ((t < 8) ? bc[(size_t)p*2048 + ci] : 0.0f);
    #pragma unroll
    for (int mi = 0; mi < 4; ++mi){
      acc[mi][ni][0]+=b; acc[mi][ni][1]+=b; acc[mi][ni][2]+=b; acc[mi][ni][3]+=b;
    }
  }

  if (t == 0){
    const int gate = r15 & 3;
    const int jr = r15 & 3;
    #pragma unroll
    for (int mi = 0; mi < 4; ++mi){
      int rl = mt*128 + wm*64 + mi*16 + g4*4 + jr;
      int n = pm ? pm[rl] : (rl < m ? rl : -1);
      #pragma unroll
      for (int ni = 0; ni < 4; ++ni){
        f32x4 a0 = acc[mi][ni];
        f32x4 a1 = shfl_xor4(a0, 1);
        f32x4 a2 = shfl_xor4(a0, 2);
        f32x4 a3 = shfl_xor4(a1, 2);
        f32x4 vi_ = sel4(a0,a1,a2,a3, gate);
        f32x4 vg_ = sel4(a0,a1,a2,a3, gate^2);
        f32x4 vo_ = sel4(a0,a1,a2,a3, gate^3);
        float xi = pick4(vi_, jr);
        float xg = pick4(vg_, jr);
        float xo = pick4(vo_, jr);
        if (n >= 0){
          int jz = nbq*32 + wn*16 + ni*4 + (r15 >> 2);
          size_t idx = (size_t)n*512 + jz;
          float cn = sigm(xi) * tanh_(xg);
          cbuf[idx] = cn;
          h0out[idx] = f2bf(sigm(xo) * tanh_(cn));
        }
      }
    }
  } else {
    #pragma unroll
    for (int mi = 0; mi < 4; ++mi)
      #pragma unroll
      for (int ni = 0; ni < 4; ++ni){
        int ci = nbq*128 + wn*64 + ni*16 + r15;
        #pragma unroll
        for (int j = 0; j < 4; ++j){
          int rl = mt*128 + wm*64 + mi*16 + g4*4 + j;
          int n = pm ? pm[rl] : (rl < m ? rl : -1);
          if (n >= 0) gx[((size_t)t*m + n)*2048 + ci] = (half_t)acc[mi][ni][j];
        }
      }
  }
}

// ---- hstep: H-GEMM only + gx add + pointwise (levels 3..0, t=1..8) ----
__global__ __launch_bounds__(256) void hstep_kernel(
    const unsigned short* __restrict__ Whh_il,
    const half_t* __restrict__ gx,
    const unsigned short* __restrict__ hi, unsigned short* __restrict__ ho,
    float* __restrict__ cbuf,
    unsigned short* __restrict__ zo, float* __restrict__ outp,
    int m, int t, int last)
{
  __shared__ unsigned short As[16384];
  __shared__ unsigned short Bs[16384];
  const int mt = blockIdx.x >> 4, nbq = blockIdx.x & 15;
  const int tid = threadIdx.x, lane = tid & 63, w = tid >> 6;
  const int wm = w >> 1, wn = w & 1;
  const int r15 = lane & 15, g4 = lane >> 4;
  const int kc = ((lane & 7) ^ (lane >> 3)) * 8;

  int nn[4];
  #pragma unroll
  for (int q = 0; q < 4; ++q){
    int rl = mt*128 + q*32 + w*8 + (lane >> 3);
    nn[q] = (rl < m) ? rl : 0;
  }
  const unsigned short* ab[4]; const unsigned short* bb[4];
  #pragma unroll
  for (int q = 0; q < 4; ++q){
    ab[q] = hi + (size_t)nn[q]*512 + kc;
    int br = nbq*128 + q*32 + w*8 + (lane >> 3);
    bb[q] = Whh_il + (size_t)br*512 + kc;
  }
  f32x4 acc[4][4] = {};
  KLOOP_BODY(ab, bb)

  #pragma unroll
  for (int mi = 0; mi < 4; ++mi)
    #pragma unroll
    for (int ni = 0; ni < 4; ++ni){
      int ci = nbq*128 + wn*64 + ni*16 + r15;
      #pragma unroll
      for (int j = 0; j < 4; ++j){
        int rl = mt*128 + wm*64 + mi*16 + g4*4 + j;
        if (rl < m) acc[mi][ni][j] += (float)gx[((size_t)t*m + rl)*2048 + ci];
      }
    }

  const int gate = r15 & 3;
  const int jr = r15 & 3;
  #pragma unroll
  for (int mi = 0; mi < 4; ++mi){
    int rl = mt*128 + wm*64 + mi*16 + g4*4 + jr;
    int n = (rl < m) ? rl : -1;
    #pragma unroll
    for (int ni = 0; ni < 4; ++ni){
      f32x4 a0 = acc[mi][ni];
      f32x4 a1 = shfl_xor4(a0, 1);
      f32x4 a2 = shfl_xor4(a0, 2);
      f32x4 a3 = shfl_xor4(a1, 2);
      f32x4 vi_ = sel4(a0,a1,a2,a3, gate);
      f32x4 vf_ = sel4(a0,a1,a2,a3, gate^1);
      f32x4 vg_ = sel4(a0,a1,a2,a3, gate^2);
      f32x4 vo_ = sel4(a0,a1,a2,a3, gate^3);
      float xi = pick4(vi_, jr), xf = pick4(vf_, jr);
      float xg = pick4(vg_, jr), xo = pick4(vo_, jr);
      if (n >= 0){
        int jz = nbq*32 + wn*16 + ni*4 + (r15 >> 2);
        size_t idx = (size_t)n*512 + jz;
        float i_ = sigm(xi), f_ = sigm(xf), g_ = tanh_(xg), o_ = sigm(xo);
        float cn = fmaf(f_, cbuf[idx], i_*g_);
        if (!last){ cbuf[idx] = cn; ho[idx] = f2bf(o_*tanh_(cn)); }
        else { if (zo) zo[idx] = f2bf(cn); else outp[idx] = cn; }
      }
    }
  }
}

// OFF = {0, 1, 9, 73, 585, 4681, 37449}
extern "C" void kernel_launch(void* const* d_in, const int* in_sizes, int n_in,
                              void* d_out, int out_size, void* d_ws, size_t ws_size,
                              hipStream_t stream)
{
  (void)in_sizes; (void)n_in; (void)out_size; (void)ws_size;
  const float* emb   = (const float*)d_in[0];
  const int*   dep   = (const int*)  d_in[1];
  const float* W_dep = (const float*)d_in[2];
  const float* b_dep = (const float*)d_in[3];
  const float* W_ih  = (const float*)d_in[4];
  const float* W_hh  = (const float*)d_in[5];
  const float* b_ih  = (const float*)d_in[6];
  const float* b_hh  = (const float*)d_in[7];
  float* out = (float*)d_out;

  unsigned short* embb   = (unsigned short*)d_ws;                  // 37449*512
  unsigned short* Wih_il = embb   + 19173888ull;                   // 2048*512
  unsigned short* Whh_il = Wih_il + 1048576ull;                    // 2048*512
  unsigned short* Wleaf  = Whh_il + 1048576ull;                    // 1024*512
  unsigned short* WdT    = Wleaf  + 524288ull;                     // 8*512*512
  unsigned short* Wcombo = WdT    + 2097152ull;                    // 8*2048*512
  unsigned short* Z0     = Wcombo + 8388608ull;                    // 32768*512
  unsigned short* Z1     = Z0     + 16777216ull;                   // 4096*512
  unsigned short* hA     = Z1     + 2097152ull;                    // 4096*512
  unsigned short* hB     = hA     + 2097152ull;                    // 4096*512
  float* cbuf  = (float*)(hB + 2097152ull);                        // 4096*512 f32
  float* bsum  = cbuf + 2097152ull;                                // 2048
  float* bc    = bsum + 2048;                                      // 8*2048
  int*  perm   = (int*)(bc + 16384);                               // 77824
  int*  tile_p = perm + 77824;                                     // 608
  int*  meta   = tile_p + 608;                                     // 40
  half_t* gx   = (half_t*)(meta + 40);                             // 9*512*2048 f16

  prep_kernel<<<2928, 256, 0, stream>>>(emb, dep, W_dep, b_dep, W_ih, W_hh, b_ih, b_hh,
                                        embb, Wih_il, Whh_il, Wleaf, WdT, bsum, bc,
                                        perm, tile_p, meta);
  combo_gemm<<<512, 256, 0, stream>>>(Wih_il, WdT, Wcombo);
  leaf_gemm<<<2048, 256, 0, stream>>>(embb + (size_t)4681*512, Wleaf, bsum, Z0);

  // level 4: 9 fused launched steps (Z0 -> Z1)
  for (int t = 0; t <= 8; ++t){
    const unsigned short* hi = (t & 1) ? hA : hB;
    unsigned short* ho       = (t & 1) ? hB : hA;
    int grid = (t < 8) ? 40*16 : 32*16;
    step_kernel<<<grid, 256, 0, stream>>>(
        embb, Wcombo, Wih_il, Whh_il, bsum, bc,
        Z0, Z1, hi, ho, cbuf, nullptr,
        (t < 8) ? (perm + t*40*128) : nullptr,
        (t < 8) ? (tile_p + t*40) : nullptr,
        (t < 8) ? (meta + 4*8 + t) : nullptr,
        32, 40, 585, 4096, t, 4);
  }

  // levels 3..0: per level, one wide gatex launch + 8 sequential H-only steps
  struct LvP { int m, MT, PB, TB, nb_, mtiles; };
  const LvP LP[4] = {
    {512, 12, 40960, 320, 73, 4},   // l=3
    {64,  8,  53248, 416, 9,  1},   // l=2
    {8,   8,  61440, 480, 1,  1},   // l=1
    {1,   8,  69632, 544, 0,  1}};  // l=0
  for (int k = 0; k < 4; ++k){
    const int l = 3 - k;
    const unsigned short* zin = (l & 1) ? Z1 : Z0;
    unsigned short* zo        = (l & 1) ? Z0 : Z1;
    gatex_kernel<<<(8*LP[k].MT + LP[k].mtiles)*16, 256, 0, stream>>>(
        embb, Wcombo, Wih_il, bsum, bc, zin, gx, hA, cbuf,
        perm + LP[k].PB, tile_p + LP[k].TB, meta + l*8,
        LP[k].MT, LP[k].m, LP[k].nb_);
    for (int t = 1; t <= 8; ++t){
      const unsigned short* hi = (t & 1) ? hA : hB;
      unsigned short* ho       = (t & 1) ? hB : hA;
      hstep_kernel<<<LP[k].mtiles*16, 256, 0, stream>>>(
          Whh_il, gx, hi, ho, cbuf,
          (l > 0) ? zo : nullptr, (l == 0) ? out : nullptr,
          LP[k].m, t, (t == 8));
    }
  }
}